// Round 1
// baseline (913.181 us; speedup 1.0000x reference)
//
#include <hip/hip_runtime.h>

// GCN: 3-layer, N=100000 nodes, E=1600000 edges, feat 128->128->128->64, fp32.
// Strategy: device-side CSR build (histogram + scan + scatter), then per layer
// fp32 GEMM (64x64 tile, LDS) and wave-per-node gather aggregation with fused
// bias+ReLU. out[i] = dis[i]*sum_e dis[col_e]*t[col_e] + dis[i]^2*t[i] + b.

#define WAVE 64

// ---------------- CSR build ----------------

__global__ void k_count(const int* __restrict__ row, int* __restrict__ deg, int e) {
    int i = blockIdx.x * blockDim.x + threadIdx.x;
    if (i < e) atomicAdd(&deg[row[i]], 1);
}

__global__ void k_dis(const int* __restrict__ deg, float* __restrict__ dis, int n) {
    int i = blockIdx.x * blockDim.x + threadIdx.x;
    if (i < n) dis[i] = rsqrtf((float)(deg[i] + 1));  // +1 self-loop
}

// per-block exclusive scan of 256 elements
__global__ void k_scan1(const int* __restrict__ deg, int* __restrict__ rp,
                        int* __restrict__ bsum, int n) {
    __shared__ int s[256];
    int tid = threadIdx.x;
    int i = blockIdx.x * 256 + tid;
    int v = (i < n) ? deg[i] : 0;
    s[tid] = v;
    __syncthreads();
    for (int off = 1; off < 256; off <<= 1) {
        int t = (tid >= off) ? s[tid - off] : 0;
        __syncthreads();
        s[tid] += t;
        __syncthreads();
    }
    if (i < n) rp[i] = s[tid] - v;  // exclusive
    if (tid == 255) bsum[blockIdx.x] = s[255];
}

// single-block exclusive scan of block sums (nb <= 512)
__global__ void k_scan2(const int* __restrict__ bsum, int* __restrict__ boffs,
                        int nb, int* __restrict__ rp, int n, int total) {
    __shared__ int s[512];
    int tid = threadIdx.x;
    int v = (tid < nb) ? bsum[tid] : 0;
    s[tid] = v;
    __syncthreads();
    for (int off = 1; off < 512; off <<= 1) {
        int t = (tid >= off) ? s[tid - off] : 0;
        __syncthreads();
        s[tid] += t;
        __syncthreads();
    }
    if (tid < nb) boffs[tid] = s[tid] - v;
    if (tid == 0) rp[n] = total;
}

__global__ void k_scan3(int* __restrict__ rp, const int* __restrict__ boffs, int n) {
    int i = blockIdx.x * blockDim.x + threadIdx.x;
    if (i < n) rp[i] += boffs[i >> 8];
}

__global__ void k_scatter(const int* __restrict__ row, const int* __restrict__ col,
                          const int* __restrict__ rp, int* __restrict__ cur,
                          int* __restrict__ csr, int e) {
    int i = blockIdx.x * blockDim.x + threadIdx.x;
    if (i < e) {
        int r = row[i];
        int pos = atomicAdd(&cur[r], 1);
        csr[rp[r] + pos] = col[i];
    }
}

// ---------------- fp32 GEMM: T[n x ldw] = H[n x 128] * W[128 x ldw] ----------
// block: 64 rows x 64 cols; 256 threads; thread tile 4 rows x 4 cols (float4).
// LDS: Hs 64x128 (32KB) + Ws 128x64 (32KB) = 64KB -> 2 blocks/CU.
// Within a wave ty in 0..3: Ws reads broadcast across ty, Hs reads broadcast
// across tx -> LDS traffic far below VALU; VALU-bound as intended.

__global__ __launch_bounds__(256) void k_gemm(const float* __restrict__ H,
                                              const float* __restrict__ W,
                                              float* __restrict__ T, int n, int ldw) {
    __shared__ float Hs[64 * 128];
    __shared__ float Ws[128 * 64];
    const int tid = threadIdx.x;
    const int row0 = blockIdx.x * 64;
    const int col0 = blockIdx.y * 64;

    // load W slice: 128 x 64
#pragma unroll
    for (int i = 0; i < 8; i++) {
        int flat = i * 256 + tid;         // 0..2047 float4s
        int r = flat >> 4, c4 = (flat & 15) * 4;
        *(float4*)&Ws[r * 64 + c4] = *(const float4*)&W[r * ldw + col0 + c4];
    }
    // load H tile: 64 x 128
#pragma unroll
    for (int i = 0; i < 8; i++) {
        int flat = i * 256 + tid;
        int r = flat >> 5, c4 = (flat & 31) * 4;
        int gr = row0 + r;
        float4 v = make_float4(0.f, 0.f, 0.f, 0.f);
        if (gr < n) v = *(const float4*)&H[gr * 128 + c4];
        *(float4*)&Hs[r * 128 + c4] = v;
    }
    __syncthreads();

    const int tx = tid & 15, ty = tid >> 4;
    const int c0 = tx * 4;
    float4 acc[4];
#pragma unroll
    for (int j = 0; j < 4; j++) acc[j] = make_float4(0.f, 0.f, 0.f, 0.f);

    for (int k = 0; k < 128; k += 4) {
        float4 w0 = *(float4*)&Ws[(k + 0) * 64 + c0];
        float4 w1 = *(float4*)&Ws[(k + 1) * 64 + c0];
        float4 w2 = *(float4*)&Ws[(k + 2) * 64 + c0];
        float4 w3 = *(float4*)&Ws[(k + 3) * 64 + c0];
#pragma unroll
        for (int j = 0; j < 4; j++) {
            float4 h = *(float4*)&Hs[(ty + 16 * j) * 128 + k];
            acc[j].x = fmaf(h.x, w0.x, acc[j].x);
            acc[j].y = fmaf(h.x, w0.y, acc[j].y);
            acc[j].z = fmaf(h.x, w0.z, acc[j].z);
            acc[j].w = fmaf(h.x, w0.w, acc[j].w);
            acc[j].x = fmaf(h.y, w1.x, acc[j].x);
            acc[j].y = fmaf(h.y, w1.y, acc[j].y);
            acc[j].z = fmaf(h.y, w1.z, acc[j].z);
            acc[j].w = fmaf(h.y, w1.w, acc[j].w);
            acc[j].x = fmaf(h.z, w2.x, acc[j].x);
            acc[j].y = fmaf(h.z, w2.y, acc[j].y);
            acc[j].z = fmaf(h.z, w2.z, acc[j].z);
            acc[j].w = fmaf(h.z, w2.w, acc[j].w);
            acc[j].x = fmaf(h.w, w3.x, acc[j].x);
            acc[j].y = fmaf(h.w, w3.y, acc[j].y);
            acc[j].z = fmaf(h.w, w3.z, acc[j].z);
            acc[j].w = fmaf(h.w, w3.w, acc[j].w);
        }
    }
#pragma unroll
    for (int j = 0; j < 4; j++) {
        int gr = row0 + ty + 16 * j;
        if (gr < n) *(float4*)&T[gr * ldw + col0 + c0] = acc[j];
    }
}

// ---------------- aggregation: one wave per node ----------------
// out[i] = dis[i] * sum_e dis[c_e]*T[c_e] + dis[i]^2 * T[i] + bias; opt ReLU.

template <int F, bool RELU>
__global__ void k_agg(const float* __restrict__ T, float* __restrict__ O,
                      const int* __restrict__ rp, const int* __restrict__ cols,
                      const float* __restrict__ dis, const float* __restrict__ bias,
                      int n) {
    int wid = (blockIdx.x * blockDim.x + threadIdx.x) >> 6;
    int lane = threadIdx.x & 63;
    if (wid >= n) return;
    int beg = rp[wid], end = rp[wid + 1];
    float di = dis[wid];
    if (F == 128) {
        float ax = 0.f, ay = 0.f;
        for (int e = beg; e < end; e++) {
            int c = cols[e];
            float wc = dis[c];
            float2 v = *(const float2*)&T[c * 128 + lane * 2];
            ax = fmaf(wc, v.x, ax);
            ay = fmaf(wc, v.y, ay);
        }
        float2 self = *(const float2*)&T[wid * 128 + lane * 2];
        float ox = di * ax + di * di * self.x + bias[lane * 2];
        float oy = di * ay + di * di * self.y + bias[lane * 2 + 1];
        if (RELU) { ox = fmaxf(ox, 0.f); oy = fmaxf(oy, 0.f); }
        float2 o; o.x = ox; o.y = oy;
        *(float2*)&O[wid * 128 + lane * 2] = o;
    } else {
        float a = 0.f;
        for (int e = beg; e < end; e++) {
            int c = cols[e];
            a = fmaf(dis[c], T[c * 64 + lane], a);
        }
        float o = di * a + di * di * T[wid * 64 + lane] + bias[lane];
        if (RELU) o = fmaxf(o, 0.f);
        O[wid * 64 + lane] = o;
    }
}

// ---------------- launch ----------------

static inline char* align256(char* p) {
    return (char*)(((uintptr_t)p + 255) & ~(uintptr_t)255);
}

extern "C" void kernel_launch(void* const* d_in, const int* in_sizes, int n_in,
                              void* d_out, int out_size, void* d_ws, size_t ws_size,
                              hipStream_t stream) {
    const float* x  = (const float*)d_in[0];
    const int*   ei = (const int*)d_in[1];
    const float* W0 = (const float*)d_in[2];
    const float* b0 = (const float*)d_in[3];
    const float* W1 = (const float*)d_in[4];
    const float* b1 = (const float*)d_in[5];
    const float* W2 = (const float*)d_in[6];
    const float* b2 = (const float*)d_in[7];

    const int Nn = in_sizes[0] / 128;
    const int Ee = in_sizes[1] / 2;
    const int* rowI = ei;
    const int* colI = ei + Ee;

    // workspace carve-up
    char* p = (char*)d_ws;
    float* bufA = (float*)p; p += (size_t)Nn * 128 * 4; p = align256(p);
    float* bufB = (float*)p; p += (size_t)Nn * 128 * 4; p = align256(p);
    int* csr    = (int*)p;   p += (size_t)Ee * 4;       p = align256(p);
    int* rp     = (int*)p;   p += (size_t)(Nn + 1) * 4; p = align256(p);
    int* deg    = (int*)p;   p += (size_t)Nn * 4;       p = align256(p);
    int* cur    = (int*)p;   p += (size_t)Nn * 4;       p = align256(p);
    float* dis  = (float*)p; p += (size_t)Nn * 4;       p = align256(p);
    int* bsum   = (int*)p;   p += 512 * 4;
    int* boffs  = (int*)p;   p += 512 * 4;

    const int eb = (Ee + 255) / 256;
    const int nb = (Nn + 255) / 256;

    hipMemsetAsync(deg, 0, (size_t)Nn * 4, stream);
    hipMemsetAsync(cur, 0, (size_t)Nn * 4, stream);

    k_count<<<eb, 256, 0, stream>>>(rowI, deg, Ee);
    k_dis<<<nb, 256, 0, stream>>>(deg, dis, Nn);
    k_scan1<<<nb, 256, 0, stream>>>(deg, rp, bsum, Nn);
    k_scan2<<<1, 512, 0, stream>>>(bsum, boffs, nb, rp, Nn, Ee);
    k_scan3<<<nb, 256, 0, stream>>>(rp, boffs, Nn);
    k_scatter<<<eb, 256, 0, stream>>>(rowI, colI, rp, cur, csr, Ee);

    dim3 g2((Nn + 63) / 64, 2);
    dim3 g1((Nn + 63) / 64, 1);
    const int ab = (Nn + 3) / 4;  // 4 waves (nodes) per 256-thread block

    // layer 0: x -> bufA -> bufB (relu)
    k_gemm<<<g2, 256, 0, stream>>>(x, W0, bufA, Nn, 128);
    k_agg<128, true><<<ab, 256, 0, stream>>>(bufA, bufB, rp, csr, dis, b0, Nn);
    // layer 1: bufB -> bufA -> bufB (relu)
    k_gemm<<<g2, 256, 0, stream>>>(bufB, W1, bufA, Nn, 128);
    k_agg<128, true><<<ab, 256, 0, stream>>>(bufA, bufB, rp, csr, dis, b1, Nn);
    // layer 2: bufB -> bufA (64 cols) -> d_out (no relu)
    k_gemm<<<g1, 256, 0, stream>>>(bufB, W2, bufA, Nn, 64);
    k_agg<64, false><<<ab, 256, 0, stream>>>(bufA, (float*)d_out, rp, csr, dis, b2, Nn);
}

// Round 2
// 735.958 us; speedup vs baseline: 1.2408x; 1.2408x over previous
//
#include <hip/hip_runtime.h>

// GCN: 3-layer, N=100000 nodes, E=1600000 edges, feat 128->128->128->64, fp32.
// Device-side CSR build (histogram + scan + scatter), per layer fp32 GEMM
// (64x64 LDS tile) and wave-per-node gather aggregation with fused bias+ReLU.
// R1: agg processes 2 edges/wave (float4/lane, 16B gathers) + unroll x2 for
// 4 gathers in flight per wave (latency-bound fix; was 1x8B dependent chain).

#define WAVE 64

// ---------------- CSR build ----------------

__global__ void k_count(const int* __restrict__ row, int* __restrict__ deg, int e) {
    int i = blockIdx.x * blockDim.x + threadIdx.x;
    if (i < e) atomicAdd(&deg[row[i]], 1);
}

__global__ void k_dis(const int* __restrict__ deg, float* __restrict__ dis, int n) {
    int i = blockIdx.x * blockDim.x + threadIdx.x;
    if (i < n) dis[i] = rsqrtf((float)(deg[i] + 1));  // +1 self-loop
}

// per-block exclusive scan of 256 elements
__global__ void k_scan1(const int* __restrict__ deg, int* __restrict__ rp,
                        int* __restrict__ bsum, int n) {
    __shared__ int s[256];
    int tid = threadIdx.x;
    int i = blockIdx.x * 256 + tid;
    int v = (i < n) ? deg[i] : 0;
    s[tid] = v;
    __syncthreads();
    for (int off = 1; off < 256; off <<= 1) {
        int t = (tid >= off) ? s[tid - off] : 0;
        __syncthreads();
        s[tid] += t;
        __syncthreads();
    }
    if (i < n) rp[i] = s[tid] - v;  // exclusive
    if (tid == 255) bsum[blockIdx.x] = s[255];
}

// single-block exclusive scan of block sums (nb <= 512)
__global__ void k_scan2(const int* __restrict__ bsum, int* __restrict__ boffs,
                        int nb, int* __restrict__ rp, int n, int total) {
    __shared__ int s[512];
    int tid = threadIdx.x;
    int v = (tid < nb) ? bsum[tid] : 0;
    s[tid] = v;
    __syncthreads();
    for (int off = 1; off < 512; off <<= 1) {
        int t = (tid >= off) ? s[tid - off] : 0;
        __syncthreads();
        s[tid] += t;
        __syncthreads();
    }
    if (tid < nb) boffs[tid] = s[tid] - v;
    if (tid == 0) rp[n] = total;
}

__global__ void k_scan3(int* __restrict__ rp, const int* __restrict__ boffs, int n) {
    int i = blockIdx.x * blockDim.x + threadIdx.x;
    if (i < n) rp[i] += boffs[i >> 8];
}

__global__ void k_scatter(const int* __restrict__ row, const int* __restrict__ col,
                          const int* __restrict__ rp, int* __restrict__ cur,
                          int* __restrict__ csr, int e) {
    int i = blockIdx.x * blockDim.x + threadIdx.x;
    if (i < e) {
        int r = row[i];
        int pos = atomicAdd(&cur[r], 1);
        csr[rp[r] + pos] = col[i];
    }
}

// ---------------- fp32 GEMM: T[n x ldw] = H[n x 128] * W[128 x ldw] ----------

__global__ __launch_bounds__(256) void k_gemm(const float* __restrict__ H,
                                              const float* __restrict__ W,
                                              float* __restrict__ T, int n, int ldw) {
    __shared__ float Hs[64 * 128];
    __shared__ float Ws[128 * 64];
    const int tid = threadIdx.x;
    const int row0 = blockIdx.x * 64;
    const int col0 = blockIdx.y * 64;

#pragma unroll
    for (int i = 0; i < 8; i++) {
        int flat = i * 256 + tid;
        int r = flat >> 4, c4 = (flat & 15) * 4;
        *(float4*)&Ws[r * 64 + c4] = *(const float4*)&W[r * ldw + col0 + c4];
    }
#pragma unroll
    for (int i = 0; i < 8; i++) {
        int flat = i * 256 + tid;
        int r = flat >> 5, c4 = (flat & 31) * 4;
        int gr = row0 + r;
        float4 v = make_float4(0.f, 0.f, 0.f, 0.f);
        if (gr < n) v = *(const float4*)&H[gr * 128 + c4];
        *(float4*)&Hs[r * 128 + c4] = v;
    }
    __syncthreads();

    const int tx = tid & 15, ty = tid >> 4;
    const int c0 = tx * 4;
    float4 acc[4];
#pragma unroll
    for (int j = 0; j < 4; j++) acc[j] = make_float4(0.f, 0.f, 0.f, 0.f);

    for (int k = 0; k < 128; k += 4) {
        float4 w0 = *(float4*)&Ws[(k + 0) * 64 + c0];
        float4 w1 = *(float4*)&Ws[(k + 1) * 64 + c0];
        float4 w2 = *(float4*)&Ws[(k + 2) * 64 + c0];
        float4 w3 = *(float4*)&Ws[(k + 3) * 64 + c0];
#pragma unroll
        for (int j = 0; j < 4; j++) {
            float4 h = *(float4*)&Hs[(ty + 16 * j) * 128 + k];
            acc[j].x = fmaf(h.x, w0.x, acc[j].x);
            acc[j].y = fmaf(h.x, w0.y, acc[j].y);
            acc[j].z = fmaf(h.x, w0.z, acc[j].z);
            acc[j].w = fmaf(h.x, w0.w, acc[j].w);
            acc[j].x = fmaf(h.y, w1.x, acc[j].x);
            acc[j].y = fmaf(h.y, w1.y, acc[j].y);
            acc[j].z = fmaf(h.y, w1.z, acc[j].z);
            acc[j].w = fmaf(h.y, w1.w, acc[j].w);
            acc[j].x = fmaf(h.z, w2.x, acc[j].x);
            acc[j].y = fmaf(h.z, w2.y, acc[j].y);
            acc[j].z = fmaf(h.z, w2.z, acc[j].z);
            acc[j].w = fmaf(h.z, w2.w, acc[j].w);
            acc[j].x = fmaf(h.w, w3.x, acc[j].x);
            acc[j].y = fmaf(h.w, w3.y, acc[j].y);
            acc[j].z = fmaf(h.w, w3.z, acc[j].z);
            acc[j].w = fmaf(h.w, w3.w, acc[j].w);
        }
    }
#pragma unroll
    for (int j = 0; j < 4; j++) {
        int gr = row0 + ty + 16 * j;
        if (gr < n) *(float4*)&T[gr * ldw + col0 + c0] = acc[j];
    }
}

// ---------------- aggregation ----------------
// out[i] = dis[i]*sum_e dis[c_e]*T[c_e] + dis[i]^2*T[i] + bias; opt ReLU.
// F=128: 2 edges/wave (32 lanes x float4 each), unroll x2 -> 4 gathers in
// flight. F=64: 4 edges/wave (16 lanes x float4), unroll x2 -> 8 in flight.

template <bool RELU>
__global__ void k_agg128(const float* __restrict__ T, float* __restrict__ O,
                         const int* __restrict__ rp, const int* __restrict__ cols,
                         const float* __restrict__ dis, const float* __restrict__ bias,
                         int n) {
    int wid = (blockIdx.x * blockDim.x + threadIdx.x) >> 6;
    int lane = threadIdx.x & 63;
    if (wid >= n) return;
    const int half = lane >> 5;          // which edge of the pair
    const int fl = (lane & 31) * 4;      // feature offset
    int beg = rp[wid], end = rp[wid + 1];
    float di = dis[wid];

    float4 acc = make_float4(0.f, 0.f, 0.f, 0.f);
    int e = beg + half;
    // unrolled: 2 edges (stride 2 within half) in flight per lane
    for (; e + 2 < end; e += 4) {
        int c0 = cols[e];
        int c1 = cols[e + 2];
        float w0 = dis[c0];
        float w1 = dis[c1];
        float4 v0 = *(const float4*)&T[(size_t)c0 * 128 + fl];
        float4 v1 = *(const float4*)&T[(size_t)c1 * 128 + fl];
        acc.x = fmaf(w0, v0.x, acc.x); acc.y = fmaf(w0, v0.y, acc.y);
        acc.z = fmaf(w0, v0.z, acc.z); acc.w = fmaf(w0, v0.w, acc.w);
        acc.x = fmaf(w1, v1.x, acc.x); acc.y = fmaf(w1, v1.y, acc.y);
        acc.z = fmaf(w1, v1.z, acc.z); acc.w = fmaf(w1, v1.w, acc.w);
    }
    if (e < end) {
        int c0 = cols[e];
        float w0 = dis[c0];
        float4 v0 = *(const float4*)&T[(size_t)c0 * 128 + fl];
        acc.x = fmaf(w0, v0.x, acc.x); acc.y = fmaf(w0, v0.y, acc.y);
        acc.z = fmaf(w0, v0.z, acc.z); acc.w = fmaf(w0, v0.w, acc.w);
    }
    // combine the two halves (feature mapping identical in both)
    acc.x += __shfl_xor(acc.x, 32);
    acc.y += __shfl_xor(acc.y, 32);
    acc.z += __shfl_xor(acc.z, 32);
    acc.w += __shfl_xor(acc.w, 32);

    if (half == 0) {
        float4 self = *(const float4*)&T[(size_t)wid * 128 + fl];
        float dii = di * di;
        float4 o;
        o.x = di * acc.x + dii * self.x + bias[fl + 0];
        o.y = di * acc.y + dii * self.y + bias[fl + 1];
        o.z = di * acc.z + dii * self.z + bias[fl + 2];
        o.w = di * acc.w + dii * self.w + bias[fl + 3];
        if (RELU) {
            o.x = fmaxf(o.x, 0.f); o.y = fmaxf(o.y, 0.f);
            o.z = fmaxf(o.z, 0.f); o.w = fmaxf(o.w, 0.f);
        }
        *(float4*)&O[(size_t)wid * 128 + fl] = o;
    }
}

template <bool RELU>
__global__ void k_agg64(const float* __restrict__ T, float* __restrict__ O,
                        const int* __restrict__ rp, const int* __restrict__ cols,
                        const float* __restrict__ dis, const float* __restrict__ bias,
                        int n) {
    int wid = (blockIdx.x * blockDim.x + threadIdx.x) >> 6;
    int lane = threadIdx.x & 63;
    if (wid >= n) return;
    const int quad = lane >> 4;          // which edge of the quartet
    const int fl = (lane & 15) * 4;      // feature offset
    int beg = rp[wid], end = rp[wid + 1];
    float di = dis[wid];

    float4 acc = make_float4(0.f, 0.f, 0.f, 0.f);
    int e = beg + quad;
    for (; e + 4 < end; e += 8) {
        int c0 = cols[e];
        int c1 = cols[e + 4];
        float w0 = dis[c0];
        float w1 = dis[c1];
        float4 v0 = *(const float4*)&T[(size_t)c0 * 64 + fl];
        float4 v1 = *(const float4*)&T[(size_t)c1 * 64 + fl];
        acc.x = fmaf(w0, v0.x, acc.x); acc.y = fmaf(w0, v0.y, acc.y);
        acc.z = fmaf(w0, v0.z, acc.z); acc.w = fmaf(w0, v0.w, acc.w);
        acc.x = fmaf(w1, v1.x, acc.x); acc.y = fmaf(w1, v1.y, acc.y);
        acc.z = fmaf(w1, v1.z, acc.z); acc.w = fmaf(w1, v1.w, acc.w);
    }
    if (e < end) {
        int c0 = cols[e];
        float w0 = dis[c0];
        float4 v0 = *(const float4*)&T[(size_t)c0 * 64 + fl];
        acc.x = fmaf(w0, v0.x, acc.x); acc.y = fmaf(w0, v0.y, acc.y);
        acc.z = fmaf(w0, v0.z, acc.z); acc.w = fmaf(w0, v0.w, acc.w);
    }
    // combine quartets
    acc.x += __shfl_xor(acc.x, 16);
    acc.y += __shfl_xor(acc.y, 16);
    acc.z += __shfl_xor(acc.z, 16);
    acc.w += __shfl_xor(acc.w, 16);
    acc.x += __shfl_xor(acc.x, 32);
    acc.y += __shfl_xor(acc.y, 32);
    acc.z += __shfl_xor(acc.z, 32);
    acc.w += __shfl_xor(acc.w, 32);

    if (quad == 0) {
        float4 self = *(const float4*)&T[(size_t)wid * 64 + fl];
        float dii = di * di;
        float4 o;
        o.x = di * acc.x + dii * self.x + bias[fl + 0];
        o.y = di * acc.y + dii * self.y + bias[fl + 1];
        o.z = di * acc.z + dii * self.z + bias[fl + 2];
        o.w = di * acc.w + dii * self.w + bias[fl + 3];
        if (RELU) {
            o.x = fmaxf(o.x, 0.f); o.y = fmaxf(o.y, 0.f);
            o.z = fmaxf(o.z, 0.f); o.w = fmaxf(o.w, 0.f);
        }
        *(float4*)&O[(size_t)wid * 64 + fl] = o;
    }
}

// ---------------- launch ----------------

static inline char* align256(char* p) {
    return (char*)(((uintptr_t)p + 255) & ~(uintptr_t)255);
}

extern "C" void kernel_launch(void* const* d_in, const int* in_sizes, int n_in,
                              void* d_out, int out_size, void* d_ws, size_t ws_size,
                              hipStream_t stream) {
    const float* x  = (const float*)d_in[0];
    const int*   ei = (const int*)d_in[1];
    const float* W0 = (const float*)d_in[2];
    const float* b0 = (const float*)d_in[3];
    const float* W1 = (const float*)d_in[4];
    const float* b1 = (const float*)d_in[5];
    const float* W2 = (const float*)d_in[6];
    const float* b2 = (const float*)d_in[7];

    const int Nn = in_sizes[0] / 128;
    const int Ee = in_sizes[1] / 2;
    const int* rowI = ei;
    const int* colI = ei + Ee;

    char* p = (char*)d_ws;
    float* bufA = (float*)p; p += (size_t)Nn * 128 * 4; p = align256(p);
    float* bufB = (float*)p; p += (size_t)Nn * 128 * 4; p = align256(p);
    int* csr    = (int*)p;   p += (size_t)Ee * 4;       p = align256(p);
    int* rp     = (int*)p;   p += (size_t)(Nn + 1) * 4; p = align256(p);
    int* deg    = (int*)p;   p += (size_t)Nn * 4;       p = align256(p);
    int* cur    = (int*)p;   p += (size_t)Nn * 4;       p = align256(p);
    float* dis  = (float*)p; p += (size_t)Nn * 4;       p = align256(p);
    int* bsum   = (int*)p;   p += 512 * 4;
    int* boffs  = (int*)p;   p += 512 * 4;

    const int eb = (Ee + 255) / 256;
    const int nb = (Nn + 255) / 256;

    hipMemsetAsync(deg, 0, (size_t)Nn * 4, stream);
    hipMemsetAsync(cur, 0, (size_t)Nn * 4, stream);

    k_count<<<eb, 256, 0, stream>>>(rowI, deg, Ee);
    k_dis<<<nb, 256, 0, stream>>>(deg, dis, Nn);
    k_scan1<<<nb, 256, 0, stream>>>(deg, rp, bsum, Nn);
    k_scan2<<<1, 512, 0, stream>>>(bsum, boffs, nb, rp, Nn, Ee);
    k_scan3<<<nb, 256, 0, stream>>>(rp, boffs, Nn);
    k_scatter<<<eb, 256, 0, stream>>>(rowI, colI, rp, cur, csr, Ee);

    dim3 g2((Nn + 63) / 64, 2);
    dim3 g1((Nn + 63) / 64, 1);
    const int ab = (Nn + 3) / 4;  // 4 waves (nodes) per 256-thread block

    k_gemm<<<g2, 256, 0, stream>>>(x, W0, bufA, Nn, 128);
    k_agg128<true><<<ab, 256, 0, stream>>>(bufA, bufB, rp, csr, dis, b0, Nn);
    k_gemm<<<g2, 256, 0, stream>>>(bufB, W1, bufA, Nn, 128);
    k_agg128<true><<<ab, 256, 0, stream>>>(bufA, bufB, rp, csr, dis, b1, Nn);
    k_gemm<<<g1, 256, 0, stream>>>(bufB, W2, bufA, Nn, 64);
    k_agg64<false><<<ab, 256, 0, stream>>>(bufA, (float*)d_out, rp, csr, dis, b2, Nn);
}

// Round 3
// 597.359 us; speedup vs baseline: 1.5287x; 1.2320x over previous
//
#include <hip/hip_runtime.h>

// GCN: 3-layer, N=100000, E=1600000, feat 128->128->128->64, fp32 in/out.
// CSR build on device, per layer: fp32 GEMM (64x64 LDS tile) writing bf16 T,
// then wave-per-node gather aggregation (bf16 gathers, fp32 accumulate) with
// fused bias+ReLU. R2: bf16 T halves gather bytes; 4 edges/wave x unroll 2.

// ---------------- helpers ----------------

__device__ inline unsigned short f2bf(float f) {
    union { float f; unsigned u; } v; v.f = f;
    unsigned r = v.u + 0x7fffu + ((v.u >> 16) & 1u);  // RNE
    return (unsigned short)(r >> 16);
}

__device__ inline void bf2x_to_f(unsigned u, float& a, float& b) {
    union { unsigned x; float f; } lo, hi;
    lo.x = u << 16; hi.x = u & 0xffff0000u;
    a = lo.f; b = hi.f;
}

__device__ inline void accum8(float* acc, uint4 u, float w) {
    float a, b;
    bf2x_to_f(u.x, a, b); acc[0] = fmaf(w, a, acc[0]); acc[1] = fmaf(w, b, acc[1]);
    bf2x_to_f(u.y, a, b); acc[2] = fmaf(w, a, acc[2]); acc[3] = fmaf(w, b, acc[3]);
    bf2x_to_f(u.z, a, b); acc[4] = fmaf(w, a, acc[4]); acc[5] = fmaf(w, b, acc[5]);
    bf2x_to_f(u.w, a, b); acc[6] = fmaf(w, a, acc[6]); acc[7] = fmaf(w, b, acc[7]);
}

// ---------------- CSR build ----------------

__global__ void k_count(const int* __restrict__ row, int* __restrict__ deg, int e) {
    int i = blockIdx.x * blockDim.x + threadIdx.x;
    if (i < e) atomicAdd(&deg[row[i]], 1);
}

__global__ void k_dis(const int* __restrict__ deg, float* __restrict__ dis, int n) {
    int i = blockIdx.x * blockDim.x + threadIdx.x;
    if (i < n) dis[i] = rsqrtf((float)(deg[i] + 1));  // +1 self-loop
}

__global__ void k_scan1(const int* __restrict__ deg, int* __restrict__ rp,
                        int* __restrict__ bsum, int n) {
    __shared__ int s[256];
    int tid = threadIdx.x;
    int i = blockIdx.x * 256 + tid;
    int v = (i < n) ? deg[i] : 0;
    s[tid] = v;
    __syncthreads();
    for (int off = 1; off < 256; off <<= 1) {
        int t = (tid >= off) ? s[tid - off] : 0;
        __syncthreads();
        s[tid] += t;
        __syncthreads();
    }
    if (i < n) rp[i] = s[tid] - v;
    if (tid == 255) bsum[blockIdx.x] = s[255];
}

__global__ void k_scan2(const int* __restrict__ bsum, int* __restrict__ boffs,
                        int nb, int* __restrict__ rp, int n, int total) {
    __shared__ int s[512];
    int tid = threadIdx.x;
    int v = (tid < nb) ? bsum[tid] : 0;
    s[tid] = v;
    __syncthreads();
    for (int off = 1; off < 512; off <<= 1) {
        int t = (tid >= off) ? s[tid - off] : 0;
        __syncthreads();
        s[tid] += t;
        __syncthreads();
    }
    if (tid < nb) boffs[tid] = s[tid] - v;
    if (tid == 0) rp[n] = total;
}

__global__ void k_scan3(int* __restrict__ rp, const int* __restrict__ boffs, int n) {
    int i = blockIdx.x * blockDim.x + threadIdx.x;
    if (i < n) rp[i] += boffs[i >> 8];
}

__global__ void k_scatter(const int* __restrict__ row, const int* __restrict__ col,
                          const int* __restrict__ rp, int* __restrict__ cur,
                          int* __restrict__ csr, int e) {
    int i = blockIdx.x * blockDim.x + threadIdx.x;
    if (i < e) {
        int r = row[i];
        int pos = atomicAdd(&cur[r], 1);
        csr[rp[r] + pos] = col[i];
    }
}

// ---------- fp32 GEMM: T_bf16[n x ldw] = H[n x 128] * W[128 x ldw] ----------

__global__ __launch_bounds__(256) void k_gemm(const float* __restrict__ H,
                                              const float* __restrict__ W,
                                              unsigned short* __restrict__ T,
                                              int n, int ldw) {
    __shared__ float Hs[64 * 128];
    __shared__ float Ws[128 * 64];
    const int tid = threadIdx.x;
    const int row0 = blockIdx.x * 64;
    const int col0 = blockIdx.y * 64;

#pragma unroll
    for (int i = 0; i < 8; i++) {
        int flat = i * 256 + tid;
        int r = flat >> 4, c4 = (flat & 15) * 4;
        *(float4*)&Ws[r * 64 + c4] = *(const float4*)&W[r * ldw + col0 + c4];
    }
#pragma unroll
    for (int i = 0; i < 8; i++) {
        int flat = i * 256 + tid;
        int r = flat >> 5, c4 = (flat & 31) * 4;
        int gr = row0 + r;
        float4 v = make_float4(0.f, 0.f, 0.f, 0.f);
        if (gr < n) v = *(const float4*)&H[(size_t)gr * 128 + c4];
        *(float4*)&Hs[r * 128 + c4] = v;
    }
    __syncthreads();

    const int tx = tid & 15, ty = tid >> 4;
    const int c0 = tx * 4;
    float4 acc[4];
#pragma unroll
    for (int j = 0; j < 4; j++) acc[j] = make_float4(0.f, 0.f, 0.f, 0.f);

    for (int k = 0; k < 128; k += 4) {
        float4 w0 = *(float4*)&Ws[(k + 0) * 64 + c0];
        float4 w1 = *(float4*)&Ws[(k + 1) * 64 + c0];
        float4 w2 = *(float4*)&Ws[(k + 2) * 64 + c0];
        float4 w3 = *(float4*)&Ws[(k + 3) * 64 + c0];
#pragma unroll
        for (int j = 0; j < 4; j++) {
            float4 h = *(float4*)&Hs[(ty + 16 * j) * 128 + k];
            acc[j].x = fmaf(h.x, w0.x, acc[j].x);
            acc[j].y = fmaf(h.x, w0.y, acc[j].y);
            acc[j].z = fmaf(h.x, w0.z, acc[j].z);
            acc[j].w = fmaf(h.x, w0.w, acc[j].w);
            acc[j].x = fmaf(h.y, w1.x, acc[j].x);
            acc[j].y = fmaf(h.y, w1.y, acc[j].y);
            acc[j].z = fmaf(h.y, w1.z, acc[j].z);
            acc[j].w = fmaf(h.y, w1.w, acc[j].w);
            acc[j].x = fmaf(h.z, w2.x, acc[j].x);
            acc[j].y = fmaf(h.z, w2.y, acc[j].y);
            acc[j].z = fmaf(h.z, w2.z, acc[j].z);
            acc[j].w = fmaf(h.z, w2.w, acc[j].w);
            acc[j].x = fmaf(h.w, w3.x, acc[j].x);
            acc[j].y = fmaf(h.w, w3.y, acc[j].y);
            acc[j].z = fmaf(h.w, w3.z, acc[j].z);
            acc[j].w = fmaf(h.w, w3.w, acc[j].w);
        }
    }
#pragma unroll
    for (int j = 0; j < 4; j++) {
        int gr = row0 + ty + 16 * j;
        if (gr < n) {
            ushort4 o;
            o.x = f2bf(acc[j].x); o.y = f2bf(acc[j].y);
            o.z = f2bf(acc[j].z); o.w = f2bf(acc[j].w);
            *(ushort4*)&T[(size_t)gr * ldw + col0 + c0] = o;
        }
    }
}

// ---------------- aggregation (bf16 T, fp32 out) ----------------
// out[i] = dis[i]*sum_e dis[c_e]*T[c_e] + dis[i]^2*T[i] + bias; opt ReLU.
// F=128: row=256B -> 4 edges/wave (16 lanes x 16B), unroll x2 = 8 in flight.
// F=64:  row=128B -> 8 edges/wave (8 lanes x 16B),  unroll x2 = 16 in flight.

template <bool RELU>
__global__ void k_agg128(const unsigned short* __restrict__ T, float* __restrict__ O,
                         const int* __restrict__ rp, const int* __restrict__ cols,
                         const float* __restrict__ dis, const float* __restrict__ bias,
                         int n) {
    int wid = (blockIdx.x * blockDim.x + threadIdx.x) >> 6;
    int lane = threadIdx.x & 63;
    if (wid >= n) return;
    const int quad = lane >> 4;          // which edge of the 4-group
    const int fl = (lane & 15) * 8;      // feature offset (8 feats/lane)
    int beg = rp[wid], end = rp[wid + 1];
    float di = dis[wid];

    float acc[8] = {0.f, 0.f, 0.f, 0.f, 0.f, 0.f, 0.f, 0.f};
    int e = beg + quad;
    for (; e + 4 < end; e += 8) {
        int c0 = cols[e];
        int c1 = cols[e + 4];
        float w0 = dis[c0];
        float w1 = dis[c1];
        uint4 u0 = *(const uint4*)&T[(size_t)c0 * 128 + fl];
        uint4 u1 = *(const uint4*)&T[(size_t)c1 * 128 + fl];
        accum8(acc, u0, w0);
        accum8(acc, u1, w1);
    }
    if (e < end) {
        int c0 = cols[e];
        float w0 = dis[c0];
        uint4 u0 = *(const uint4*)&T[(size_t)c0 * 128 + fl];
        accum8(acc, u0, w0);
    }
#pragma unroll
    for (int k = 0; k < 8; k++) {
        acc[k] += __shfl_xor(acc[k], 16);
        acc[k] += __shfl_xor(acc[k], 32);
    }
    if (quad == 0) {
        uint4 us = *(const uint4*)&T[(size_t)wid * 128 + fl];
        float self[8];
        bf2x_to_f(us.x, self[0], self[1]);
        bf2x_to_f(us.y, self[2], self[3]);
        bf2x_to_f(us.z, self[4], self[5]);
        bf2x_to_f(us.w, self[6], self[7]);
        float4 bA = *(const float4*)&bias[fl];
        float4 bB = *(const float4*)&bias[fl + 4];
        float bb[8] = {bA.x, bA.y, bA.z, bA.w, bB.x, bB.y, bB.z, bB.w};
        float dii = di * di;
        float o[8];
#pragma unroll
        for (int k = 0; k < 8; k++) {
            o[k] = fmaf(di, acc[k], fmaf(dii, self[k], bb[k]));
            if (RELU) o[k] = fmaxf(o[k], 0.f);
        }
        *(float4*)&O[(size_t)wid * 128 + fl] = make_float4(o[0], o[1], o[2], o[3]);
        *(float4*)&O[(size_t)wid * 128 + fl + 4] = make_float4(o[4], o[5], o[6], o[7]);
    }
}

template <bool RELU>
__global__ void k_agg64(const unsigned short* __restrict__ T, float* __restrict__ O,
                        const int* __restrict__ rp, const int* __restrict__ cols,
                        const float* __restrict__ dis, const float* __restrict__ bias,
                        int n) {
    int wid = (blockIdx.x * blockDim.x + threadIdx.x) >> 6;
    int lane = threadIdx.x & 63;
    if (wid >= n) return;
    const int oct = lane >> 3;           // which edge of the 8-group
    const int fl = (lane & 7) * 8;       // feature offset (8 feats/lane)
    int beg = rp[wid], end = rp[wid + 1];
    float di = dis[wid];

    float acc[8] = {0.f, 0.f, 0.f, 0.f, 0.f, 0.f, 0.f, 0.f};
    int e = beg + oct;
    for (; e + 8 < end; e += 16) {
        int c0 = cols[e];
        int c1 = cols[e + 8];
        float w0 = dis[c0];
        float w1 = dis[c1];
        uint4 u0 = *(const uint4*)&T[(size_t)c0 * 64 + fl];
        uint4 u1 = *(const uint4*)&T[(size_t)c1 * 64 + fl];
        accum8(acc, u0, w0);
        accum8(acc, u1, w1);
    }
    if (e < end) {
        int c0 = cols[e];
        float w0 = dis[c0];
        uint4 u0 = *(const uint4*)&T[(size_t)c0 * 64 + fl];
        accum8(acc, u0, w0);
    }
#pragma unroll
    for (int k = 0; k < 8; k++) {
        acc[k] += __shfl_xor(acc[k], 8);
        acc[k] += __shfl_xor(acc[k], 16);
        acc[k] += __shfl_xor(acc[k], 32);
    }
    if (oct == 0) {
        uint4 us = *(const uint4*)&T[(size_t)wid * 64 + fl];
        float self[8];
        bf2x_to_f(us.x, self[0], self[1]);
        bf2x_to_f(us.y, self[2], self[3]);
        bf2x_to_f(us.z, self[4], self[5]);
        bf2x_to_f(us.w, self[6], self[7]);
        float4 bA = *(const float4*)&bias[fl];
        float4 bB = *(const float4*)&bias[fl + 4];
        float bb[8] = {bA.x, bA.y, bA.z, bA.w, bB.x, bB.y, bB.z, bB.w};
        float dii = di * di;
        float o[8];
#pragma unroll
        for (int k = 0; k < 8; k++) {
            o[k] = fmaf(di, acc[k], fmaf(dii, self[k], bb[k]));
            if (RELU) o[k] = fmaxf(o[k], 0.f);
        }
        *(float4*)&O[(size_t)wid * 64 + fl] = make_float4(o[0], o[1], o[2], o[3]);
        *(float4*)&O[(size_t)wid * 64 + fl + 4] = make_float4(o[4], o[5], o[6], o[7]);
    }
}

// ---------------- launch ----------------

static inline char* align256(char* p) {
    return (char*)(((uintptr_t)p + 255) & ~(uintptr_t)255);
}

extern "C" void kernel_launch(void* const* d_in, const int* in_sizes, int n_in,
                              void* d_out, int out_size, void* d_ws, size_t ws_size,
                              hipStream_t stream) {
    const float* x  = (const float*)d_in[0];
    const int*   ei = (const int*)d_in[1];
    const float* W0 = (const float*)d_in[2];
    const float* b0 = (const float*)d_in[3];
    const float* W1 = (const float*)d_in[4];
    const float* b1 = (const float*)d_in[5];
    const float* W2 = (const float*)d_in[6];
    const float* b2 = (const float*)d_in[7];

    const int Nn = in_sizes[0] / 128;
    const int Ee = in_sizes[1] / 2;
    const int* rowI = ei;
    const int* colI = ei + Ee;

    char* p = (char*)d_ws;
    float* bufF = (float*)p;            p += (size_t)Nn * 128 * 4; p = align256(p);
    unsigned short* Tb = (unsigned short*)p; p += (size_t)Nn * 128 * 2; p = align256(p);
    int* csr    = (int*)p;   p += (size_t)Ee * 4;       p = align256(p);
    int* rp     = (int*)p;   p += (size_t)(Nn + 1) * 4; p = align256(p);
    int* deg    = (int*)p;   p += (size_t)Nn * 4;       p = align256(p);
    int* cur    = (int*)p;   p += (size_t)Nn * 4;       p = align256(p);
    float* dis  = (float*)p; p += (size_t)Nn * 4;       p = align256(p);
    int* bsum   = (int*)p;   p += 512 * 4;
    int* boffs  = (int*)p;   p += 512 * 4;

    const int eb = (Ee + 255) / 256;
    const int nb = (Nn + 255) / 256;

    hipMemsetAsync(deg, 0, (size_t)Nn * 4, stream);
    hipMemsetAsync(cur, 0, (size_t)Nn * 4, stream);

    k_count<<<eb, 256, 0, stream>>>(rowI, deg, Ee);
    k_dis<<<nb, 256, 0, stream>>>(deg, dis, Nn);
    k_scan1<<<nb, 256, 0, stream>>>(deg, rp, bsum, Nn);
    k_scan2<<<1, 512, 0, stream>>>(bsum, boffs, nb, rp, Nn, Ee);
    k_scan3<<<nb, 256, 0, stream>>>(rp, boffs, Nn);
    k_scatter<<<eb, 256, 0, stream>>>(rowI, colI, rp, cur, csr, Ee);

    dim3 g2((Nn + 63) / 64, 2);
    dim3 g1((Nn + 63) / 64, 1);
    const int ab = (Nn + 3) / 4;  // 4 waves (nodes) per 256-thread block

    k_gemm<<<g2, 256, 0, stream>>>(x, W0, Tb, Nn, 128);
    k_agg128<true><<<ab, 256, 0, stream>>>(Tb, bufF, rp, csr, dis, b0, Nn);
    k_gemm<<<g2, 256, 0, stream>>>(bufF, W1, Tb, Nn, 128);
    k_agg128<true><<<ab, 256, 0, stream>>>(Tb, bufF, rp, csr, dis, b1, Nn);
    k_gemm<<<g1, 256, 0, stream>>>(bufF, W2, Tb, Nn, 64);
    k_agg64<false><<<ab, 256, 0, stream>>>(Tb, (float*)d_out, rp, csr, dis, b2, Nn);
}

// Round 4
// 515.909 us; speedup vs baseline: 1.7700x; 1.1579x over previous
//
#include <hip/hip_runtime.h>

// GCN: 3-layer, N=100000, E=1600000, feat 128->128->128->64, fp32 in/out.
// CSR build on device, per layer: fp32 GEMM (64x64 LDS tile) writing bf16 T,
// then wave-per-node gather aggregation (bf16 gathers, fp32 accumulate) with
// fused bias+ReLU.
// R3: k_count saves atomicAdd's return as pos[i] (edge rank within row);
// k_scatter becomes atomic-free (coalesced reads + one random 4B store/edge).

// ---------------- helpers ----------------

__device__ inline unsigned short f2bf(float f) {
    union { float f; unsigned u; } v; v.f = f;
    unsigned r = v.u + 0x7fffu + ((v.u >> 16) & 1u);  // RNE
    return (unsigned short)(r >> 16);
}

__device__ inline void bf2x_to_f(unsigned u, float& a, float& b) {
    union { unsigned x; float f; } lo, hi;
    lo.x = u << 16; hi.x = u & 0xffff0000u;
    a = lo.f; b = hi.f;
}

__device__ inline void accum8(float* acc, uint4 u, float w) {
    float a, b;
    bf2x_to_f(u.x, a, b); acc[0] = fmaf(w, a, acc[0]); acc[1] = fmaf(w, b, acc[1]);
    bf2x_to_f(u.y, a, b); acc[2] = fmaf(w, a, acc[2]); acc[3] = fmaf(w, b, acc[3]);
    bf2x_to_f(u.z, a, b); acc[4] = fmaf(w, a, acc[4]); acc[5] = fmaf(w, b, acc[5]);
    bf2x_to_f(u.w, a, b); acc[6] = fmaf(w, a, acc[6]); acc[7] = fmaf(w, b, acc[7]);
}

// ---------------- CSR build ----------------

// pos[i] = rank of edge i within its row (atomicAdd old value)
__global__ void k_count(const int* __restrict__ row, int* __restrict__ deg,
                        int* __restrict__ pos, int e) {
    int i = blockIdx.x * blockDim.x + threadIdx.x;
    if (i < e) pos[i] = atomicAdd(&deg[row[i]], 1);
}

__global__ void k_dis(const int* __restrict__ deg, float* __restrict__ dis, int n) {
    int i = blockIdx.x * blockDim.x + threadIdx.x;
    if (i < n) dis[i] = rsqrtf((float)(deg[i] + 1));  // +1 self-loop
}

__global__ void k_scan1(const int* __restrict__ deg, int* __restrict__ rp,
                        int* __restrict__ bsum, int n) {
    __shared__ int s[256];
    int tid = threadIdx.x;
    int i = blockIdx.x * 256 + tid;
    int v = (i < n) ? deg[i] : 0;
    s[tid] = v;
    __syncthreads();
    for (int off = 1; off < 256; off <<= 1) {
        int t = (tid >= off) ? s[tid - off] : 0;
        __syncthreads();
        s[tid] += t;
        __syncthreads();
    }
    if (i < n) rp[i] = s[tid] - v;
    if (tid == 255) bsum[blockIdx.x] = s[255];
}

__global__ void k_scan2(const int* __restrict__ bsum, int* __restrict__ boffs,
                        int nb, int* __restrict__ rp, int n, int total) {
    __shared__ int s[512];
    int tid = threadIdx.x;
    int v = (tid < nb) ? bsum[tid] : 0;
    s[tid] = v;
    __syncthreads();
    for (int off = 1; off < 512; off <<= 1) {
        int t = (tid >= off) ? s[tid - off] : 0;
        __syncthreads();
        s[tid] += t;
        __syncthreads();
    }
    if (tid < nb) boffs[tid] = s[tid] - v;
    if (tid == 0) rp[n] = total;
}

__global__ void k_scan3(int* __restrict__ rp, const int* __restrict__ boffs, int n) {
    int i = blockIdx.x * blockDim.x + threadIdx.x;
    if (i < n) rp[i] += boffs[i >> 8];
}

// atomic-free scatter: all reads coalesced, one random 4B store per edge
__global__ void k_scatter(const int* __restrict__ row, const int* __restrict__ col,
                          const int* __restrict__ rp, const int* __restrict__ pos,
                          int* __restrict__ csr, int e) {
    int i = blockIdx.x * blockDim.x + threadIdx.x;
    if (i < e) {
        int r = row[i];
        csr[rp[r] + pos[i]] = col[i];
    }
}

// ---------- fp32 GEMM: T_bf16[n x ldw] = H[n x 128] * W[128 x ldw] ----------

__global__ __launch_bounds__(256) void k_gemm(const float* __restrict__ H,
                                              const float* __restrict__ W,
                                              unsigned short* __restrict__ T,
                                              int n, int ldw) {
    __shared__ float Hs[64 * 128];
    __shared__ float Ws[128 * 64];
    const int tid = threadIdx.x;
    const int row0 = blockIdx.x * 64;
    const int col0 = blockIdx.y * 64;

#pragma unroll
    for (int i = 0; i < 8; i++) {
        int flat = i * 256 + tid;
        int r = flat >> 4, c4 = (flat & 15) * 4;
        *(float4*)&Ws[r * 64 + c4] = *(const float4*)&W[r * ldw + col0 + c4];
    }
#pragma unroll
    for (int i = 0; i < 8; i++) {
        int flat = i * 256 + tid;
        int r = flat >> 5, c4 = (flat & 31) * 4;
        int gr = row0 + r;
        float4 v = make_float4(0.f, 0.f, 0.f, 0.f);
        if (gr < n) v = *(const float4*)&H[(size_t)gr * 128 + c4];
        *(float4*)&Hs[r * 128 + c4] = v;
    }
    __syncthreads();

    const int tx = tid & 15, ty = tid >> 4;
    const int c0 = tx * 4;
    float4 acc[4];
#pragma unroll
    for (int j = 0; j < 4; j++) acc[j] = make_float4(0.f, 0.f, 0.f, 0.f);

    for (int k = 0; k < 128; k += 4) {
        float4 w0 = *(float4*)&Ws[(k + 0) * 64 + c0];
        float4 w1 = *(float4*)&Ws[(k + 1) * 64 + c0];
        float4 w2 = *(float4*)&Ws[(k + 2) * 64 + c0];
        float4 w3 = *(float4*)&Ws[(k + 3) * 64 + c0];
#pragma unroll
        for (int j = 0; j < 4; j++) {
            float4 h = *(float4*)&Hs[(ty + 16 * j) * 128 + k];
            acc[j].x = fmaf(h.x, w0.x, acc[j].x);
            acc[j].y = fmaf(h.x, w0.y, acc[j].y);
            acc[j].z = fmaf(h.x, w0.z, acc[j].z);
            acc[j].w = fmaf(h.x, w0.w, acc[j].w);
            acc[j].x = fmaf(h.y, w1.x, acc[j].x);
            acc[j].y = fmaf(h.y, w1.y, acc[j].y);
            acc[j].z = fmaf(h.y, w1.z, acc[j].z);
            acc[j].w = fmaf(h.y, w1.w, acc[j].w);
            acc[j].x = fmaf(h.z, w2.x, acc[j].x);
            acc[j].y = fmaf(h.z, w2.y, acc[j].y);
            acc[j].z = fmaf(h.z, w2.z, acc[j].z);
            acc[j].w = fmaf(h.z, w2.w, acc[j].w);
            acc[j].x = fmaf(h.w, w3.x, acc[j].x);
            acc[j].y = fmaf(h.w, w3.y, acc[j].y);
            acc[j].z = fmaf(h.w, w3.z, acc[j].z);
            acc[j].w = fmaf(h.w, w3.w, acc[j].w);
        }
    }
#pragma unroll
    for (int j = 0; j < 4; j++) {
        int gr = row0 + ty + 16 * j;
        if (gr < n) {
            ushort4 o;
            o.x = f2bf(acc[j].x); o.y = f2bf(acc[j].y);
            o.z = f2bf(acc[j].z); o.w = f2bf(acc[j].w);
            *(ushort4*)&T[(size_t)gr * ldw + col0 + c0] = o;
        }
    }
}

// ---------------- aggregation (bf16 T, fp32 out) ----------------

template <bool RELU>
__global__ void k_agg128(const unsigned short* __restrict__ T, float* __restrict__ O,
                         const int* __restrict__ rp, const int* __restrict__ cols,
                         const float* __restrict__ dis, const float* __restrict__ bias,
                         int n) {
    int wid = (blockIdx.x * blockDim.x + threadIdx.x) >> 6;
    int lane = threadIdx.x & 63;
    if (wid >= n) return;
    const int quad = lane >> 4;          // which edge of the 4-group
    const int fl = (lane & 15) * 8;      // feature offset (8 feats/lane)
    int beg = rp[wid], end = rp[wid + 1];
    float di = dis[wid];

    float acc[8] = {0.f, 0.f, 0.f, 0.f, 0.f, 0.f, 0.f, 0.f};
    int e = beg + quad;
    for (; e + 4 < end; e += 8) {
        int c0 = cols[e];
        int c1 = cols[e + 4];
        float w0 = dis[c0];
        float w1 = dis[c1];
        uint4 u0 = *(const uint4*)&T[(size_t)c0 * 128 + fl];
        uint4 u1 = *(const uint4*)&T[(size_t)c1 * 128 + fl];
        accum8(acc, u0, w0);
        accum8(acc, u1, w1);
    }
    if (e < end) {
        int c0 = cols[e];
        float w0 = dis[c0];
        uint4 u0 = *(const uint4*)&T[(size_t)c0 * 128 + fl];
        accum8(acc, u0, w0);
    }
#pragma unroll
    for (int k = 0; k < 8; k++) {
        acc[k] += __shfl_xor(acc[k], 16);
        acc[k] += __shfl_xor(acc[k], 32);
    }
    if (quad == 0) {
        uint4 us = *(const uint4*)&T[(size_t)wid * 128 + fl];
        float self[8];
        bf2x_to_f(us.x, self[0], self[1]);
        bf2x_to_f(us.y, self[2], self[3]);
        bf2x_to_f(us.z, self[4], self[5]);
        bf2x_to_f(us.w, self[6], self[7]);
        float4 bA = *(const float4*)&bias[fl];
        float4 bB = *(const float4*)&bias[fl + 4];
        float bb[8] = {bA.x, bA.y, bA.z, bA.w, bB.x, bB.y, bB.z, bB.w};
        float dii = di * di;
        float o[8];
#pragma unroll
        for (int k = 0; k < 8; k++) {
            o[k] = fmaf(di, acc[k], fmaf(dii, self[k], bb[k]));
            if (RELU) o[k] = fmaxf(o[k], 0.f);
        }
        *(float4*)&O[(size_t)wid * 128 + fl] = make_float4(o[0], o[1], o[2], o[3]);
        *(float4*)&O[(size_t)wid * 128 + fl + 4] = make_float4(o[4], o[5], o[6], o[7]);
    }
}

template <bool RELU>
__global__ void k_agg64(const unsigned short* __restrict__ T, float* __restrict__ O,
                        const int* __restrict__ rp, const int* __restrict__ cols,
                        const float* __restrict__ dis, const float* __restrict__ bias,
                        int n) {
    int wid = (blockIdx.x * blockDim.x + threadIdx.x) >> 6;
    int lane = threadIdx.x & 63;
    if (wid >= n) return;
    const int oct = lane >> 3;           // which edge of the 8-group
    const int fl = (lane & 7) * 8;       // feature offset (8 feats/lane)
    int beg = rp[wid], end = rp[wid + 1];
    float di = dis[wid];

    float acc[8] = {0.f, 0.f, 0.f, 0.f, 0.f, 0.f, 0.f, 0.f};
    int e = beg + oct;
    for (; e + 8 < end; e += 16) {
        int c0 = cols[e];
        int c1 = cols[e + 8];
        float w0 = dis[c0];
        float w1 = dis[c1];
        uint4 u0 = *(const uint4*)&T[(size_t)c0 * 64 + fl];
        uint4 u1 = *(const uint4*)&T[(size_t)c1 * 64 + fl];
        accum8(acc, u0, w0);
        accum8(acc, u1, w1);
    }
    if (e < end) {
        int c0 = cols[e];
        float w0 = dis[c0];
        uint4 u0 = *(const uint4*)&T[(size_t)c0 * 64 + fl];
        accum8(acc, u0, w0);
    }
#pragma unroll
    for (int k = 0; k < 8; k++) {
        acc[k] += __shfl_xor(acc[k], 8);
        acc[k] += __shfl_xor(acc[k], 16);
        acc[k] += __shfl_xor(acc[k], 32);
    }
    if (oct == 0) {
        uint4 us = *(const uint4*)&T[(size_t)wid * 64 + fl];
        float self[8];
        bf2x_to_f(us.x, self[0], self[1]);
        bf2x_to_f(us.y, self[2], self[3]);
        bf2x_to_f(us.z, self[4], self[5]);
        bf2x_to_f(us.w, self[6], self[7]);
        float4 bA = *(const float4*)&bias[fl];
        float4 bB = *(const float4*)&bias[fl + 4];
        float bb[8] = {bA.x, bA.y, bA.z, bA.w, bB.x, bB.y, bB.z, bB.w};
        float dii = di * di;
        float o[8];
#pragma unroll
        for (int k = 0; k < 8; k++) {
            o[k] = fmaf(di, acc[k], fmaf(dii, self[k], bb[k]));
            if (RELU) o[k] = fmaxf(o[k], 0.f);
        }
        *(float4*)&O[(size_t)wid * 64 + fl] = make_float4(o[0], o[1], o[2], o[3]);
        *(float4*)&O[(size_t)wid * 64 + fl + 4] = make_float4(o[4], o[5], o[6], o[7]);
    }
}

// ---------------- launch ----------------

static inline char* align256(char* p) {
    return (char*)(((uintptr_t)p + 255) & ~(uintptr_t)255);
}

extern "C" void kernel_launch(void* const* d_in, const int* in_sizes, int n_in,
                              void* d_out, int out_size, void* d_ws, size_t ws_size,
                              hipStream_t stream) {
    const float* x  = (const float*)d_in[0];
    const int*   ei = (const int*)d_in[1];
    const float* W0 = (const float*)d_in[2];
    const float* b0 = (const float*)d_in[3];
    const float* W1 = (const float*)d_in[4];
    const float* b1 = (const float*)d_in[5];
    const float* W2 = (const float*)d_in[6];
    const float* b2 = (const float*)d_in[7];

    const int Nn = in_sizes[0] / 128;
    const int Ee = in_sizes[1] / 2;
    const int* rowI = ei;
    const int* colI = ei + Ee;

    char* p = (char*)d_ws;
    float* bufF = (float*)p;            p += (size_t)Nn * 128 * 4; p = align256(p);
    unsigned short* Tb = (unsigned short*)p; p += (size_t)Nn * 128 * 2; p = align256(p);
    int* csr    = (int*)p;   p += (size_t)Ee * 4;       p = align256(p);
    int* pos    = (int*)p;   p += (size_t)Ee * 4;       p = align256(p);
    int* rp     = (int*)p;   p += (size_t)(Nn + 1) * 4; p = align256(p);
    int* deg    = (int*)p;   p += (size_t)Nn * 4;       p = align256(p);
    float* dis  = (float*)p; p += (size_t)Nn * 4;       p = align256(p);
    int* bsum   = (int*)p;   p += 512 * 4;
    int* boffs  = (int*)p;   p += 512 * 4;

    const int eb = (Ee + 255) / 256;
    const int nb = (Nn + 255) / 256;

    hipMemsetAsync(deg, 0, (size_t)Nn * 4, stream);

    k_count<<<eb, 256, 0, stream>>>(rowI, deg, pos, Ee);
    k_dis<<<nb, 256, 0, stream>>>(deg, dis, Nn);
    k_scan1<<<nb, 256, 0, stream>>>(deg, rp, bsum, Nn);
    k_scan2<<<1, 512, 0, stream>>>(bsum, boffs, nb, rp, Nn, Ee);
    k_scan3<<<nb, 256, 0, stream>>>(rp, boffs, Nn);
    k_scatter<<<eb, 256, 0, stream>>>(rowI, colI, rp, pos, csr, Ee);

    dim3 g2((Nn + 63) / 64, 2);
    dim3 g1((Nn + 63) / 64, 1);
    const int ab = (Nn + 3) / 4;  // 4 waves (nodes) per 256-thread block

    k_gemm<<<g2, 256, 0, stream>>>(x, W0, Tb, Nn, 128);
    k_agg128<true><<<ab, 256, 0, stream>>>(Tb, bufF, rp, csr, dis, b0, Nn);
    k_gemm<<<g2, 256, 0, stream>>>(bufF, W1, Tb, Nn, 128);
    k_agg128<true><<<ab, 256, 0, stream>>>(Tb, bufF, rp, csr, dis, b1, Nn);
    k_gemm<<<g1, 256, 0, stream>>>(bufF, W2, Tb, Nn, 64);
    k_agg64<false><<<ab, 256, 0, stream>>>(Tb, (float*)d_out, rp, csr, dis, b2, Nn);
}

// Round 5
// 496.307 us; speedup vs baseline: 1.8400x; 1.0395x over previous
//
#include <hip/hip_runtime.h>

// GCN: 3-layer, N=100000, E=1600000, feat 128->128->128->64, fp32 in/out.
// CSR build on device. Per layer: split-bf16 MFMA GEMM (C = Ah@Bh + Ah@Bl +
// Al@Bh, fp32-class accuracy) writing bf16 T, then wave-per-node gather
// aggregation (bf16 gathers, fp32 accumulate) emitting next layer's hi/lo
// bf16 split directly. R4: MFMA GEMM replaces fp32 VALU GEMM (47 TF capped,
// 6.4M LDS conflict cycles); W register-resident; XOR-swizzled A staging.

typedef __attribute__((ext_vector_type(8))) short bf16x8;
typedef __attribute__((ext_vector_type(4))) float floatx4;

// ---------------- helpers ----------------

__device__ inline unsigned short f2bf(float f) {
    union { float f; unsigned u; } v; v.f = f;
    unsigned r = v.u + 0x7fffu + ((v.u >> 16) & 1u);  // RNE
    return (unsigned short)(r >> 16);
}

__device__ inline float bf2f(unsigned short h) {
    union { unsigned u; float f; } v; v.u = (unsigned)h << 16;
    return v.f;
}

__device__ inline void split_bf(float v, unsigned short& h, unsigned short& l) {
    h = f2bf(v);
    l = f2bf(v - bf2f(h));
}

__device__ inline void bf2x_to_f(unsigned u, float& a, float& b) {
    union { unsigned x; float f; } lo, hi;
    lo.x = u << 16; hi.x = u & 0xffff0000u;
    a = lo.f; b = hi.f;
}

__device__ inline void accum8(float* acc, uint4 u, float w) {
    float a, b;
    bf2x_to_f(u.x, a, b); acc[0] = fmaf(w, a, acc[0]); acc[1] = fmaf(w, b, acc[1]);
    bf2x_to_f(u.y, a, b); acc[2] = fmaf(w, a, acc[2]); acc[3] = fmaf(w, b, acc[3]);
    bf2x_to_f(u.z, a, b); acc[4] = fmaf(w, a, acc[4]); acc[5] = fmaf(w, b, acc[5]);
    bf2x_to_f(u.w, a, b); acc[6] = fmaf(w, a, acc[6]); acc[7] = fmaf(w, b, acc[7]);
}

// ---------------- CSR build ----------------

__global__ void k_count(const int* __restrict__ row, int* __restrict__ deg,
                        int* __restrict__ pos, int e) {
    int i = blockIdx.x * blockDim.x + threadIdx.x;
    if (i < e) pos[i] = atomicAdd(&deg[row[i]], 1);
}

__global__ void k_dis(const int* __restrict__ deg, float* __restrict__ dis, int n) {
    int i = blockIdx.x * blockDim.x + threadIdx.x;
    if (i < n) dis[i] = rsqrtf((float)(deg[i] + 1));  // +1 self-loop
}

__global__ void k_scan1(const int* __restrict__ deg, int* __restrict__ rp,
                        int* __restrict__ bsum, int n) {
    __shared__ int s[256];
    int tid = threadIdx.x;
    int i = blockIdx.x * 256 + tid;
    int v = (i < n) ? deg[i] : 0;
    s[tid] = v;
    __syncthreads();
    for (int off = 1; off < 256; off <<= 1) {
        int t = (tid >= off) ? s[tid - off] : 0;
        __syncthreads();
        s[tid] += t;
        __syncthreads();
    }
    if (i < n) rp[i] = s[tid] - v;
    if (tid == 255) bsum[blockIdx.x] = s[255];
}

__global__ void k_scan2(const int* __restrict__ bsum, int* __restrict__ boffs,
                        int nb, int* __restrict__ rp, int n, int total) {
    __shared__ int s[512];
    int tid = threadIdx.x;
    int v = (tid < nb) ? bsum[tid] : 0;
    s[tid] = v;
    __syncthreads();
    for (int off = 1; off < 512; off <<= 1) {
        int t = (tid >= off) ? s[tid - off] : 0;
        __syncthreads();
        s[tid] += t;
        __syncthreads();
    }
    if (tid < nb) boffs[tid] = s[tid] - v;
    if (tid == 0) rp[n] = total;
}

__global__ void k_scan3(int* __restrict__ rp, const int* __restrict__ boffs, int n) {
    int i = blockIdx.x * blockDim.x + threadIdx.x;
    if (i < n) rp[i] += boffs[i >> 8];
}

__global__ void k_scatter(const int* __restrict__ row, const int* __restrict__ col,
                          const int* __restrict__ rp, const int* __restrict__ pos,
                          int* __restrict__ csr, int e) {
    int i = blockIdx.x * blockDim.x + threadIdx.x;
    if (i < e) {
        int r = row[i];
        csr[rp[r] + pos[i]] = col[i];
    }
}

// ---------------- input prep: fp32 -> bf16 hi/lo split ----------------

__global__ void k_prepX(const float* __restrict__ X, unsigned short* __restrict__ Xhi,
                        unsigned short* __restrict__ Xlo, int total4) {
    int id = blockIdx.x * blockDim.x + threadIdx.x;
    if (id < total4) {
        float4 v = ((const float4*)X)[id];
        ushort4 h, l;
        split_bf(v.x, h.x, l.x);
        split_bf(v.y, h.y, l.y);
        split_bf(v.z, h.z, l.z);
        split_bf(v.w, h.w, l.w);
        ((ushort4*)Xhi)[id] = h;
        ((ushort4*)Xlo)[id] = l;
    }
}

// W[k][n] (128 x ldw) -> Wt hi/lo [n][k] (ldw x 128), bf16 split
__global__ void k_prepW(const float* __restrict__ W, unsigned short* __restrict__ Wthi,
                        unsigned short* __restrict__ Wtlo, int ldw) {
    int id = blockIdx.x * blockDim.x + threadIdx.x;
    if (id < 128 * ldw) {
        int k = id / ldw, nn = id - k * ldw;
        unsigned short h, l;
        split_bf(W[id], h, l);
        Wthi[nn * 128 + k] = h;
        Wtlo[nn * 128 + k] = l;
    }
}

// ---------------- split-bf16 MFMA GEMM ----------------
// T_bf16[n x LDW] = (Ah+Al)[n x 128] @ W[128 x LDW], W pre-transposed/split.
// Block: 256 thr = 4 waves (2x2), tile 64x64. A hi/lo staged in 32KB LDS with
// XOR-swizzled 16B chunks; B frags register-resident (W tiny, L2-hot).
// Verified layouts only: mfma_f32_16x16x32_bf16, A[m=lane&15][k=quad*8+j],
// C/D col=lane&15 row=quad*4+reg.

template <int NB>  // LDW = NB*64
__global__ __launch_bounds__(256) void k_gemm_mfma(
    const unsigned short* __restrict__ Ahi, const unsigned short* __restrict__ Alo,
    const unsigned short* __restrict__ Wthi, const unsigned short* __restrict__ Wtlo,
    unsigned short* __restrict__ T, int n) {
    const int LDW = NB * 64;
    __shared__ unsigned short Ah_s[64 * 128];
    __shared__ unsigned short Al_s[64 * 128];
    const int tid = threadIdx.x;
    const int bid = blockIdx.x;
    const int bx = (NB == 2) ? (bid >> 1) : bid;   // adjacent blocks share A tile
    const int by = (NB == 2) ? (bid & 1) : 0;
    const int row0 = bx * 64;
    const int col0 = by * 64;

    const int wave = tid >> 6, lane = tid & 63;
    const int ln = lane & 15, quad = lane >> 4;
    const int m0 = (wave >> 1) * 32;   // wave's row quadrant within 64
    const int nq0 = (wave & 1) * 32;   // wave's col quadrant within 64

    // B fragments: [k-step][n-tile], hi and lo. B[k][n]: lane holds
    // n=lane&15, k=quad*8+j -> contiguous 8 bf16 in Wt[n][k].
    bf16x8 Bh[4][2], Bl[4][2];
#pragma unroll
    for (int s = 0; s < 4; s++)
#pragma unroll
        for (int j = 0; j < 2; j++) {
            int ncol = col0 + nq0 + 16 * j + ln;
            int koff = 32 * s + quad * 8;
            Bh[s][j] = *(const bf16x8*)&Wthi[ncol * 128 + koff];
            Bl[s][j] = *(const bf16x8*)&Wtlo[ncol * 128 + koff];
        }

    // stage A tile hi/lo (64 x 128 bf16 each), XOR-swizzled 16B chunks
#pragma unroll
    for (int k = 0; k < 4; k++) {
        int id = k * 256 + tid;
        int r = id >> 4, c = id & 15;
        int gr = row0 + r;
        uint4 vh = make_uint4(0, 0, 0, 0), vl = make_uint4(0, 0, 0, 0);
        if (gr < n) {
            vh = *(const uint4*)&Ahi[(size_t)gr * 128 + c * 8];
            vl = *(const uint4*)&Alo[(size_t)gr * 128 + c * 8];
        }
        int pc = c ^ (r & 15);
        *(uint4*)&Ah_s[r * 128 + pc * 8] = vh;
        *(uint4*)&Al_s[r * 128 + pc * 8] = vl;
    }
    __syncthreads();

    floatx4 acc[2][2];
#pragma unroll
    for (int i = 0; i < 2; i++)
#pragma unroll
        for (int j = 0; j < 2; j++) acc[i][j] = (floatx4){0.f, 0.f, 0.f, 0.f};

#pragma unroll
    for (int s = 0; s < 4; s++) {
        bf16x8 ah[2], al[2];
#pragma unroll
        for (int i = 0; i < 2; i++) {
            // row r = m0+16i+ln (r&15 == ln), chunk (4s+quad)^ln
            int off = (m0 + 16 * i + ln) * 128 + ((4 * s + quad) ^ ln) * 8;
            ah[i] = *(const bf16x8*)&Ah_s[off];
            al[i] = *(const bf16x8*)&Al_s[off];
        }
#pragma unroll
        for (int i = 0; i < 2; i++)
#pragma unroll
            for (int j = 0; j < 2; j++) {
                acc[i][j] = __builtin_amdgcn_mfma_f32_16x16x32_bf16(
                    ah[i], Bh[s][j], acc[i][j], 0, 0, 0);
                acc[i][j] = __builtin_amdgcn_mfma_f32_16x16x32_bf16(
                    ah[i], Bl[s][j], acc[i][j], 0, 0, 0);
                acc[i][j] = __builtin_amdgcn_mfma_f32_16x16x32_bf16(
                    al[i], Bh[s][j], acc[i][j], 0, 0, 0);
            }
    }

#pragma unroll
    for (int i = 0; i < 2; i++)
#pragma unroll
        for (int j = 0; j < 2; j++)
#pragma unroll
            for (int reg = 0; reg < 4; reg++) {
                int gr = row0 + m0 + 16 * i + quad * 4 + reg;
                int gc = col0 + nq0 + 16 * j + ln;
                if (gr < n) T[(size_t)gr * LDW + gc] = f2bf(acc[i][j][reg]);
            }
}

// ---------------- aggregation (bf16 T in, hi/lo bf16 out) ----------------

__global__ void k_agg128(const unsigned short* __restrict__ T,
                         unsigned short* __restrict__ Ohi,
                         unsigned short* __restrict__ Olo,
                         const int* __restrict__ rp, const int* __restrict__ cols,
                         const float* __restrict__ dis, const float* __restrict__ bias,
                         int n) {
    int wid = (blockIdx.x * blockDim.x + threadIdx.x) >> 6;
    int lane = threadIdx.x & 63;
    if (wid >= n) return;
    const int quad = lane >> 4;
    const int fl = (lane & 15) * 8;
    int beg = rp[wid], end = rp[wid + 1];
    float di = dis[wid];

    float acc[8] = {0.f, 0.f, 0.f, 0.f, 0.f, 0.f, 0.f, 0.f};
    int e = beg + quad;
    for (; e + 4 < end; e += 8) {
        int c0 = cols[e];
        int c1 = cols[e + 4];
        float w0 = dis[c0];
        float w1 = dis[c1];
        uint4 u0 = *(const uint4*)&T[(size_t)c0 * 128 + fl];
        uint4 u1 = *(const uint4*)&T[(size_t)c1 * 128 + fl];
        accum8(acc, u0, w0);
        accum8(acc, u1, w1);
    }
    if (e < end) {
        int c0 = cols[e];
        float w0 = dis[c0];
        uint4 u0 = *(const uint4*)&T[(size_t)c0 * 128 + fl];
        accum8(acc, u0, w0);
    }
#pragma unroll
    for (int k = 0; k < 8; k++) {
        acc[k] += __shfl_xor(acc[k], 16);
        acc[k] += __shfl_xor(acc[k], 32);
    }
    if (quad == 0) {
        uint4 us = *(const uint4*)&T[(size_t)wid * 128 + fl];
        float self[8];
        bf2x_to_f(us.x, self[0], self[1]);
        bf2x_to_f(us.y, self[2], self[3]);
        bf2x_to_f(us.z, self[4], self[5]);
        bf2x_to_f(us.w, self[6], self[7]);
        float4 bA = *(const float4*)&bias[fl];
        float4 bB = *(const float4*)&bias[fl + 4];
        float bb[8] = {bA.x, bA.y, bA.z, bA.w, bB.x, bB.y, bB.z, bB.w};
        float dii = di * di;
        unsigned short h[8], l[8];
#pragma unroll
        for (int k = 0; k < 8; k++) {
            float o = fmaf(di, acc[k], fmaf(dii, self[k], bb[k]));
            o = fmaxf(o, 0.f);  // relu (both 128-wide layers have it)
            split_bf(o, h[k], l[k]);
        }
        ushort4 h0 = {h[0], h[1], h[2], h[3]}, h1 = {h[4], h[5], h[6], h[7]};
        ushort4 l0 = {l[0], l[1], l[2], l[3]}, l1 = {l[4], l[5], l[6], l[7]};
        *(ushort4*)&Ohi[(size_t)wid * 128 + fl] = h0;
        *(ushort4*)&Ohi[(size_t)wid * 128 + fl + 4] = h1;
        *(ushort4*)&Olo[(size_t)wid * 128 + fl] = l0;
        *(ushort4*)&Olo[(size_t)wid * 128 + fl + 4] = l1;
    }
}

__global__ void k_agg64(const unsigned short* __restrict__ T, float* __restrict__ O,
                        const int* __restrict__ rp, const int* __restrict__ cols,
                        const float* __restrict__ dis, const float* __restrict__ bias,
                        int n) {
    int wid = (blockIdx.x * blockDim.x + threadIdx.x) >> 6;
    int lane = threadIdx.x & 63;
    if (wid >= n) return;
    const int oct = lane >> 3;
    const int fl = (lane & 7) * 8;
    int beg = rp[wid], end = rp[wid + 1];
    float di = dis[wid];

    float acc[8] = {0.f, 0.f, 0.f, 0.f, 0.f, 0.f, 0.f, 0.f};
    int e = beg + oct;
    for (; e + 8 < end; e += 16) {
        int c0 = cols[e];
        int c1 = cols[e + 8];
        float w0 = dis[c0];
        float w1 = dis[c1];
        uint4 u0 = *(const uint4*)&T[(size_t)c0 * 64 + fl];
        uint4 u1 = *(const uint4*)&T[(size_t)c1 * 64 + fl];
        accum8(acc, u0, w0);
        accum8(acc, u1, w1);
    }
    if (e < end) {
        int c0 = cols[e];
        float w0 = dis[c0];
        uint4 u0 = *(const uint4*)&T[(size_t)c0 * 64 + fl];
        accum8(acc, u0, w0);
    }
#pragma unroll
    for (int k = 0; k < 8; k++) {
        acc[k] += __shfl_xor(acc[k], 8);
        acc[k] += __shfl_xor(acc[k], 16);
        acc[k] += __shfl_xor(acc[k], 32);
    }
    if (oct == 0) {
        uint4 us = *(const uint4*)&T[(size_t)wid * 64 + fl];
        float self[8];
        bf2x_to_f(us.x, self[0], self[1]);
        bf2x_to_f(us.y, self[2], self[3]);
        bf2x_to_f(us.z, self[4], self[5]);
        bf2x_to_f(us.w, self[6], self[7]);
        float4 bA = *(const float4*)&bias[fl];
        float4 bB = *(const float4*)&bias[fl + 4];
        float bb[8] = {bA.x, bA.y, bA.z, bA.w, bB.x, bB.y, bB.z, bB.w};
        float dii = di * di;
        float o[8];
#pragma unroll
        for (int k = 0; k < 8; k++)
            o[k] = fmaf(di, acc[k], fmaf(dii, self[k], bb[k]));
        *(float4*)&O[(size_t)wid * 64 + fl] = make_float4(o[0], o[1], o[2], o[3]);
        *(float4*)&O[(size_t)wid * 64 + fl + 4] = make_float4(o[4], o[5], o[6], o[7]);
    }
}

// ---------------- launch ----------------

static inline char* align256(char* p) {
    return (char*)(((uintptr_t)p + 255) & ~(uintptr_t)255);
}

extern "C" void kernel_launch(void* const* d_in, const int* in_sizes, int n_in,
                              void* d_out, int out_size, void* d_ws, size_t ws_size,
                              hipStream_t stream) {
    const float* x  = (const float*)d_in[0];
    const int*   ei = (const int*)d_in[1];
    const float* W0 = (const float*)d_in[2];
    const float* b0 = (const float*)d_in[3];
    const float* W1 = (const float*)d_in[4];
    const float* b1 = (const float*)d_in[5];
    const float* W2 = (const float*)d_in[6];
    const float* b2 = (const float*)d_in[7];

    const int Nn = in_sizes[0] / 128;
    const int Ee = in_sizes[1] / 2;
    const int* rowI = ei;
    const int* colI = ei + Ee;

    char* p = (char*)d_ws;
    unsigned short* Tb  = (unsigned short*)p; p += (size_t)Nn * 128 * 2; p = align256(p);
    unsigned short* Ahi = (unsigned short*)p; p += (size_t)Nn * 128 * 2; p = align256(p);
    unsigned short* Alo = (unsigned short*)p; p += (size_t)Nn * 128 * 2; p = align256(p);
    int* csr    = (int*)p;   p += (size_t)Ee * 4;       p = align256(p);
    int* pos    = (int*)p;   p += (size_t)Ee * 4;       p = align256(p);
    int* rp     = (int*)p;   p += (size_t)(Nn + 1) * 4; p = align256(p);
    int* deg    = (int*)p;   p += (size_t)Nn * 4;       p = align256(p);
    float* dis  = (float*)p; p += (size_t)Nn * 4;       p = align256(p);
    int* bsum   = (int*)p;   p += 512 * 4;
    int* boffs  = (int*)p;   p += 512 * 4;
    unsigned short* Wt0h = (unsigned short*)p; p += 128 * 128 * 2;
    unsigned short* Wt0l = (unsigned short*)p; p += 128 * 128 * 2;
    unsigned short* Wt1h = (unsigned short*)p; p += 128 * 128 * 2;
    unsigned short* Wt1l = (unsigned short*)p; p += 128 * 128 * 2;
    unsigned short* Wt2h = (unsigned short*)p; p += 64 * 128 * 2;
    unsigned short* Wt2l = (unsigned short*)p; p += 64 * 128 * 2;

    const int eb = (Ee + 255) / 256;
    const int nb = (Nn + 255) / 256;

    hipMemsetAsync(deg, 0, (size_t)Nn * 4, stream);

    k_count<<<eb, 256, 0, stream>>>(rowI, deg, pos, Ee);
    k_dis<<<nb, 256, 0, stream>>>(deg, dis, Nn);
    k_scan1<<<nb, 256, 0, stream>>>(deg, rp, bsum, Nn);
    k_scan2<<<1, 512, 0, stream>>>(bsum, boffs, nb, rp, Nn, Ee);
    k_scan3<<<nb, 256, 0, stream>>>(rp, boffs, Nn);
    k_scatter<<<eb, 256, 0, stream>>>(rowI, colI, rp, pos, csr, Ee);

    k_prepX<<<(Nn * 32 + 255) / 256, 256, 0, stream>>>(x, Ahi, Alo, Nn * 32);
    k_prepW<<<64, 256, 0, stream>>>(W0, Wt0h, Wt0l, 128);
    k_prepW<<<64, 256, 0, stream>>>(W1, Wt1h, Wt1l, 128);
    k_prepW<<<32, 256, 0, stream>>>(W2, Wt2h, Wt2l, 64);

    const int gx = (Nn + 63) / 64;
    const int ab = (Nn + 3) / 4;  // 4 waves (nodes) per 256-thread block

    k_gemm_mfma<2><<<2 * gx, 256, 0, stream>>>(Ahi, Alo, Wt0h, Wt0l, Tb, Nn);
    k_agg128<<<ab, 256, 0, stream>>>(Tb, Ahi, Alo, rp, csr, dis, b0, Nn);
    k_gemm_mfma<2><<<2 * gx, 256, 0, stream>>>(Ahi, Alo, Wt1h, Wt1l, Tb, Nn);
    k_agg128<<<ab, 256, 0, stream>>>(Tb, Ahi, Alo, rp, csr, dis, b1, Nn);
    k_gemm_mfma<1><<<gx, 256, 0, stream>>>(Ahi, Alo, Wt2h, Wt2l, Tb, Nn);
    k_agg64<<<ab, 256, 0, stream>>>(Tb, (float*)d_out, rp, csr, dis, b2, Nn);
}

// Round 6
// 493.193 us; speedup vs baseline: 1.8516x; 1.0063x over previous
//
#include <hip/hip_runtime.h>

// GCN: 3-layer, N=100000, E=1600000, feat 128->128->128->64, fp32 in/out.
// CSR build on device. Per layer: split-bf16 MFMA GEMM (C = Ah@Bh + Ah@Bl +
// Al@Bh) whose epilogue writes T'[c] = dis[c] * (H@W)[c] in bf16; then
// wave-per-node gather aggregation: out[i] = dis[i]*(sum_e T'[col_e] + T'[i])
// + bias (dis[col] folded into T' -> no per-edge dis gather), 4-deep gather
// pipelining. Aggs emit next layer's hi/lo bf16 split directly.

typedef __attribute__((ext_vector_type(8))) short bf16x8;
typedef __attribute__((ext_vector_type(4))) float floatx4;

// ---------------- helpers ----------------

__device__ inline unsigned short f2bf(float f) {
    union { float f; unsigned u; } v; v.f = f;
    unsigned r = v.u + 0x7fffu + ((v.u >> 16) & 1u);  // RNE
    return (unsigned short)(r >> 16);
}

__device__ inline float bf2f(unsigned short h) {
    union { unsigned u; float f; } v; v.u = (unsigned)h << 16;
    return v.f;
}

__device__ inline void split_bf(float v, unsigned short& h, unsigned short& l) {
    h = f2bf(v);
    l = f2bf(v - bf2f(h));
}

__device__ inline void bf2x_to_f(unsigned u, float& a, float& b) {
    union { unsigned x; float f; } lo, hi;
    lo.x = u << 16; hi.x = u & 0xffff0000u;
    a = lo.f; b = hi.f;
}

__device__ inline void add8(float* acc, uint4 u) {
    float a, b;
    bf2x_to_f(u.x, a, b); acc[0] += a; acc[1] += b;
    bf2x_to_f(u.y, a, b); acc[2] += a; acc[3] += b;
    bf2x_to_f(u.z, a, b); acc[4] += a; acc[5] += b;
    bf2x_to_f(u.w, a, b); acc[6] += a; acc[7] += b;
}

// ---------------- CSR build ----------------

__global__ void k_count(const int* __restrict__ row, int* __restrict__ deg,
                        int* __restrict__ pos, int e) {
    int i = blockIdx.x * blockDim.x + threadIdx.x;
    if (i < e) pos[i] = atomicAdd(&deg[row[i]], 1);
}

__global__ void k_dis(const int* __restrict__ deg, float* __restrict__ dis, int n) {
    int i = blockIdx.x * blockDim.x + threadIdx.x;
    if (i < n) dis[i] = rsqrtf((float)(deg[i] + 1));  // +1 self-loop
}

__global__ void k_scan1(const int* __restrict__ deg, int* __restrict__ rp,
                        int* __restrict__ bsum, int n) {
    __shared__ int s[256];
    int tid = threadIdx.x;
    int i = blockIdx.x * 256 + tid;
    int v = (i < n) ? deg[i] : 0;
    s[tid] = v;
    __syncthreads();
    for (int off = 1; off < 256; off <<= 1) {
        int t = (tid >= off) ? s[tid - off] : 0;
        __syncthreads();
        s[tid] += t;
        __syncthreads();
    }
    if (i < n) rp[i] = s[tid] - v;
    if (tid == 255) bsum[blockIdx.x] = s[255];
}

__global__ void k_scan2(const int* __restrict__ bsum, int* __restrict__ boffs,
                        int nb, int* __restrict__ rp, int n, int total) {
    __shared__ int s[512];
    int tid = threadIdx.x;
    int v = (tid < nb) ? bsum[tid] : 0;
    s[tid] = v;
    __syncthreads();
    for (int off = 1; off < 512; off <<= 1) {
        int t = (tid >= off) ? s[tid - off] : 0;
        __syncthreads();
        s[tid] += t;
        __syncthreads();
    }
    if (tid < nb) boffs[tid] = s[tid] - v;
    if (tid == 0) rp[n] = total;
}

__global__ void k_scan3(int* __restrict__ rp, const int* __restrict__ boffs, int n) {
    int i = blockIdx.x * blockDim.x + threadIdx.x;
    if (i < n) rp[i] += boffs[i >> 8];
}

__global__ void k_scatter(const int* __restrict__ row, const int* __restrict__ col,
                          const int* __restrict__ rp, const int* __restrict__ pos,
                          int* __restrict__ csr, int e) {
    int i = blockIdx.x * blockDim.x + threadIdx.x;
    if (i < e) {
        int r = row[i];
        csr[rp[r] + pos[i]] = col[i];
    }
}

// ---------------- input prep: fp32 -> bf16 hi/lo split ----------------

__global__ void k_prepX(const float* __restrict__ X, unsigned short* __restrict__ Xhi,
                        unsigned short* __restrict__ Xlo, int total4) {
    int id = blockIdx.x * blockDim.x + threadIdx.x;
    if (id < total4) {
        float4 v = ((const float4*)X)[id];
        ushort4 h, l;
        split_bf(v.x, h.x, l.x);
        split_bf(v.y, h.y, l.y);
        split_bf(v.z, h.z, l.z);
        split_bf(v.w, h.w, l.w);
        ((ushort4*)Xhi)[id] = h;
        ((ushort4*)Xlo)[id] = l;
    }
}

// W[k][n] (128 x ldw) -> Wt hi/lo [n][k] (ldw x 128), bf16 split
__global__ void k_prepW(const float* __restrict__ W, unsigned short* __restrict__ Wthi,
                        unsigned short* __restrict__ Wtlo, int ldw) {
    int id = blockIdx.x * blockDim.x + threadIdx.x;
    if (id < 128 * ldw) {
        int k = id / ldw, nn = id - k * ldw;
        unsigned short h, l;
        split_bf(W[id], h, l);
        Wthi[nn * 128 + k] = h;
        Wtlo[nn * 128 + k] = l;
    }
}

// ---------------- split-bf16 MFMA GEMM, epilogue scales by dis ----------------
// T'[r] = dis[r] * ((Ah+Al)[n x 128] @ W[128 x LDW])[r], bf16 out.
// Verified layouts: mfma_f32_16x16x32_bf16, A[m=lane&15][k=quad*8+j],
// C/D col=lane&15 row=quad*4+reg.

template <int NB>  // LDW = NB*64
__global__ __launch_bounds__(256) void k_gemm_mfma(
    const unsigned short* __restrict__ Ahi, const unsigned short* __restrict__ Alo,
    const unsigned short* __restrict__ Wthi, const unsigned short* __restrict__ Wtlo,
    const float* __restrict__ dis, unsigned short* __restrict__ T, int n) {
    const int LDW = NB * 64;
    __shared__ unsigned short Ah_s[64 * 128];
    __shared__ unsigned short Al_s[64 * 128];
    const int tid = threadIdx.x;
    const int bid = blockIdx.x;
    const int bx = (NB == 2) ? (bid >> 1) : bid;   // adjacent blocks share A tile
    const int by = (NB == 2) ? (bid & 1) : 0;
    const int row0 = bx * 64;
    const int col0 = by * 64;

    const int wave = tid >> 6, lane = tid & 63;
    const int ln = lane & 15, quad = lane >> 4;
    const int m0 = (wave >> 1) * 32;
    const int nq0 = (wave & 1) * 32;

    bf16x8 Bh[4][2], Bl[4][2];
#pragma unroll
    for (int s = 0; s < 4; s++)
#pragma unroll
        for (int j = 0; j < 2; j++) {
            int ncol = col0 + nq0 + 16 * j + ln;
            int koff = 32 * s + quad * 8;
            Bh[s][j] = *(const bf16x8*)&Wthi[ncol * 128 + koff];
            Bl[s][j] = *(const bf16x8*)&Wtlo[ncol * 128 + koff];
        }

#pragma unroll
    for (int k = 0; k < 4; k++) {
        int id = k * 256 + tid;
        int r = id >> 4, c = id & 15;
        int gr = row0 + r;
        uint4 vh = make_uint4(0, 0, 0, 0), vl = make_uint4(0, 0, 0, 0);
        if (gr < n) {
            vh = *(const uint4*)&Ahi[(size_t)gr * 128 + c * 8];
            vl = *(const uint4*)&Alo[(size_t)gr * 128 + c * 8];
        }
        int pc = c ^ (r & 15);
        *(uint4*)&Ah_s[r * 128 + pc * 8] = vh;
        *(uint4*)&Al_s[r * 128 + pc * 8] = vl;
    }
    __syncthreads();

    floatx4 acc[2][2];
#pragma unroll
    for (int i = 0; i < 2; i++)
#pragma unroll
        for (int j = 0; j < 2; j++) acc[i][j] = (floatx4){0.f, 0.f, 0.f, 0.f};

#pragma unroll
    for (int s = 0; s < 4; s++) {
        bf16x8 ah[2], al[2];
#pragma unroll
        for (int i = 0; i < 2; i++) {
            int off = (m0 + 16 * i + ln) * 128 + ((4 * s + quad) ^ ln) * 8;
            ah[i] = *(const bf16x8*)&Ah_s[off];
            al[i] = *(const bf16x8*)&Al_s[off];
        }
#pragma unroll
        for (int i = 0; i < 2; i++)
#pragma unroll
            for (int j = 0; j < 2; j++) {
                acc[i][j] = __builtin_amdgcn_mfma_f32_16x16x32_bf16(
                    ah[i], Bh[s][j], acc[i][j], 0, 0, 0);
                acc[i][j] = __builtin_amdgcn_mfma_f32_16x16x32_bf16(
                    ah[i], Bl[s][j], acc[i][j], 0, 0, 0);
                acc[i][j] = __builtin_amdgcn_mfma_f32_16x16x32_bf16(
                    al[i], Bh[s][j], acc[i][j], 0, 0, 0);
            }
    }

#pragma unroll
    for (int i = 0; i < 2; i++)
#pragma unroll
        for (int reg = 0; reg < 4; reg++) {
            int gr = row0 + m0 + 16 * i + quad * 4 + reg;
            if (gr < n) {
                float ds = dis[gr];
#pragma unroll
                for (int j = 0; j < 2; j++) {
                    int gc = col0 + nq0 + 16 * j + ln;
                    T[(size_t)gr * LDW + gc] = f2bf(ds * acc[i][j][reg]);
                }
            }
        }
}

// ---------------- aggregation (bf16 T' in) ----------------
// acc = sum_e T'[col_e]; out = dis[i]*(acc + T'[i]) + bias.
// F=128: 4 edges/wave (16 lanes x 16B), unroll x4 = 16 edges/iter in flight.

__global__ void k_agg128(const unsigned short* __restrict__ T,
                         unsigned short* __restrict__ Ohi,
                         unsigned short* __restrict__ Olo,
                         const int* __restrict__ rp, const int* __restrict__ cols,
                         const float* __restrict__ dis, const float* __restrict__ bias,
                         int n) {
    int wid = (blockIdx.x * blockDim.x + threadIdx.x) >> 6;
    int lane = threadIdx.x & 63;
    if (wid >= n) return;
    const int quad = lane >> 4;
    const int fl = (lane & 15) * 8;
    int beg = rp[wid], end = rp[wid + 1];

    float acc[8] = {0.f, 0.f, 0.f, 0.f, 0.f, 0.f, 0.f, 0.f};
    int e = beg + quad;
    for (; e + 12 < end; e += 16) {
        int c0 = cols[e];
        int c1 = cols[e + 4];
        int c2 = cols[e + 8];
        int c3 = cols[e + 12];
        uint4 u0 = *(const uint4*)&T[(size_t)c0 * 128 + fl];
        uint4 u1 = *(const uint4*)&T[(size_t)c1 * 128 + fl];
        uint4 u2 = *(const uint4*)&T[(size_t)c2 * 128 + fl];
        uint4 u3 = *(const uint4*)&T[(size_t)c3 * 128 + fl];
        add8(acc, u0);
        add8(acc, u1);
        add8(acc, u2);
        add8(acc, u3);
    }
    for (; e < end; e += 4) {
        int c = cols[e];
        uint4 u = *(const uint4*)&T[(size_t)c * 128 + fl];
        add8(acc, u);
    }
#pragma unroll
    for (int k = 0; k < 8; k++) {
        acc[k] += __shfl_xor(acc[k], 16);
        acc[k] += __shfl_xor(acc[k], 32);
    }
    if (quad == 0) {
        uint4 us = *(const uint4*)&T[(size_t)wid * 128 + fl];
        add8(acc, us);  // self term (already dis-scaled)
        float di = dis[wid];
        float4 bA = *(const float4*)&bias[fl];
        float4 bB = *(const float4*)&bias[fl + 4];
        float bb[8] = {bA.x, bA.y, bA.z, bA.w, bB.x, bB.y, bB.z, bB.w};
        unsigned short h[8], l[8];
#pragma unroll
        for (int k = 0; k < 8; k++) {
            float o = fmaf(di, acc[k], bb[k]);
            o = fmaxf(o, 0.f);  // relu (both 128-wide layers)
            split_bf(o, h[k], l[k]);
        }
        ushort4 h0 = {h[0], h[1], h[2], h[3]}, h1 = {h[4], h[5], h[6], h[7]};
        ushort4 l0 = {l[0], l[1], l[2], l[3]}, l1 = {l[4], l[5], l[6], l[7]};
        *(ushort4*)&Ohi[(size_t)wid * 128 + fl] = h0;
        *(ushort4*)&Ohi[(size_t)wid * 128 + fl + 4] = h1;
        *(ushort4*)&Olo[(size_t)wid * 128 + fl] = l0;
        *(ushort4*)&Olo[(size_t)wid * 128 + fl + 4] = l1;
    }
}

__global__ void k_agg64(const unsigned short* __restrict__ T, float* __restrict__ O,
                        const int* __restrict__ rp, const int* __restrict__ cols,
                        const float* __restrict__ dis, const float* __restrict__ bias,
                        int n) {
    int wid = (blockIdx.x * blockDim.x + threadIdx.x) >> 6;
    int lane = threadIdx.x & 63;
    if (wid >= n) return;
    const int oct = lane >> 3;
    const int fl = (lane & 7) * 8;
    int beg = rp[wid], end = rp[wid + 1];

    float acc[8] = {0.f, 0.f, 0.f, 0.f, 0.f, 0.f, 0.f, 0.f};
    int e = beg + oct;
    for (; e + 8 < end; e += 16) {
        int c0 = cols[e];
        int c1 = cols[e + 8];
        uint4 u0 = *(const uint4*)&T[(size_t)c0 * 64 + fl];
        uint4 u1 = *(const uint4*)&T[(size_t)c1 * 64 + fl];
        add8(acc, u0);
        add8(acc, u1);
    }
    if (e < end) {
        int c = cols[e];
        uint4 u = *(const uint4*)&T[(size_t)c * 64 + fl];
        add8(acc, u);
    }
#pragma unroll
    for (int k = 0; k < 8; k++) {
        acc[k] += __shfl_xor(acc[k], 8);
        acc[k] += __shfl_xor(acc[k], 16);
        acc[k] += __shfl_xor(acc[k], 32);
    }
    if (oct == 0) {
        uint4 us = *(const uint4*)&T[(size_t)wid * 64 + fl];
        add8(acc, us);  // self term
        float di = dis[wid];
        float4 bA = *(const float4*)&bias[fl];
        float4 bB = *(const float4*)&bias[fl + 4];
        float bb[8] = {bA.x, bA.y, bA.z, bA.w, bB.x, bB.y, bB.z, bB.w};
        float o[8];
#pragma unroll
        for (int k = 0; k < 8; k++)
            o[k] = fmaf(di, acc[k], bb[k]);
        *(float4*)&O[(size_t)wid * 64 + fl] = make_float4(o[0], o[1], o[2], o[3]);
        *(float4*)&O[(size_t)wid * 64 + fl + 4] = make_float4(o[4], o[5], o[6], o[7]);
    }
}

// ---------------- launch ----------------

static inline char* align256(char* p) {
    return (char*)(((uintptr_t)p + 255) & ~(uintptr_t)255);
}

extern "C" void kernel_launch(void* const* d_in, const int* in_sizes, int n_in,
                              void* d_out, int out_size, void* d_ws, size_t ws_size,
                              hipStream_t stream) {
    const float* x  = (const float*)d_in[0];
    const int*   ei = (const int*)d_in[1];
    const float* W0 = (const float*)d_in[2];
    const float* b0 = (const float*)d_in[3];
    const float* W1 = (const float*)d_in[4];
    const float* b1 = (const float*)d_in[5];
    const float* W2 = (const float*)d_in[6];
    const float* b2 = (const float*)d_in[7];

    const int Nn = in_sizes[0] / 128;
    const int Ee = in_sizes[1] / 2;
    const int* rowI = ei;
    const int* colI = ei + Ee;

    char* p = (char*)d_ws;
    unsigned short* Tb  = (unsigned short*)p; p += (size_t)Nn * 128 * 2; p = align256(p);
    unsigned short* Ahi = (unsigned short*)p; p += (size_t)Nn * 128 * 2; p = align256(p);
    unsigned short* Alo = (unsigned short*)p; p += (size_t)Nn * 128 * 2; p = align256(p);
    int* csr    = (int*)p;   p += (size_t)Ee * 4;       p = align256(p);
    int* pos    = (int*)p;   p += (size_t)Ee * 4;       p = align256(p);
    int* rp     = (int*)p;   p += (size_t)(Nn + 1) * 4; p = align256(p);
    int* deg    = (int*)p;   p += (size_t)Nn * 4;       p = align256(p);
    float* dis  = (float*)p; p += (size_t)Nn * 4;       p = align256(p);
    int* bsum   = (int*)p;   p += 512 * 4;
    int* boffs  = (int*)p;   p += 512 * 4;
    unsigned short* Wt0h = (unsigned short*)p; p += 128 * 128 * 2;
    unsigned short* Wt0l = (unsigned short*)p; p += 128 * 128 * 2;
    unsigned short* Wt1h = (unsigned short*)p; p += 128 * 128 * 2;
    unsigned short* Wt1l = (unsigned short*)p; p += 128 * 128 * 2;
    unsigned short* Wt2h = (unsigned short*)p; p += 64 * 128 * 2;
    unsigned short* Wt2l = (unsigned short*)p; p += 64 * 128 * 2;

    const int eb = (Ee + 255) / 256;
    const int nb = (Nn + 255) / 256;

    hipMemsetAsync(deg, 0, (size_t)Nn * 4, stream);

    k_count<<<eb, 256, 0, stream>>>(rowI, deg, pos, Ee);
    k_dis<<<nb, 256, 0, stream>>>(deg, dis, Nn);
    k_scan1<<<nb, 256, 0, stream>>>(deg, rp, bsum, Nn);
    k_scan2<<<1, 512, 0, stream>>>(bsum, boffs, nb, rp, Nn, Ee);
    k_scan3<<<nb, 256, 0, stream>>>(rp, boffs, Nn);
    k_scatter<<<eb, 256, 0, stream>>>(rowI, colI, rp, pos, csr, Ee);

    k_prepX<<<(Nn * 32 + 255) / 256, 256, 0, stream>>>(x, Ahi, Alo, Nn * 32);
    k_prepW<<<64, 256, 0, stream>>>(W0, Wt0h, Wt0l, 128);
    k_prepW<<<64, 256, 0, stream>>>(W1, Wt1h, Wt1l, 128);
    k_prepW<<<32, 256, 0, stream>>>(W2, Wt2h, Wt2l, 64);

    const int gx = (Nn + 63) / 64;
    const int ab = (Nn + 3) / 4;  // 4 waves (nodes) per 256-thread block

    k_gemm_mfma<2><<<2 * gx, 256, 0, stream>>>(Ahi, Alo, Wt0h, Wt0l, dis, Tb, Nn);
    k_agg128<<<ab, 256, 0, stream>>>(Tb, Ahi, Alo, rp, csr, dis, b0, Nn);
    k_gemm_mfma<2><<<2 * gx, 256, 0, stream>>>(Ahi, Alo, Wt1h, Wt1l, dis, Tb, Nn);
    k_agg128<<<ab, 256, 0, stream>>>(Tb, Ahi, Alo, rp, csr, dis, b1, Nn);
    k_gemm_mfma<1><<<gx, 256, 0, stream>>>(Ahi, Alo, Wt2h, Wt2l, dis, Tb, Nn);
    k_agg64<<<ab, 256, 0, stream>>>(Tb, (float*)d_out, rp, csr, dis, b2, Nn);
}